// Round 1
// baseline (797.275 us; speedup 1.0000x reference)
//
#include <hip/hip_runtime.h>
#include <hip/hip_bf16.h>

#define DEV __device__ __forceinline__

typedef __bf16 bf16x8 __attribute__((ext_vector_type(8)));
typedef float f32x4 __attribute__((ext_vector_type(4)));
typedef __hip_bfloat16 hbf;

constexpr int Dm = 1024;
constexpr int Hh = 16;
constexpr int Ss = 2048;
constexpr int Bb = 4;
constexpr int DFm = 4096;

DEV unsigned short f2bfu(float f) {
  hbf h = __float2bfloat16(f);
  return __builtin_bit_cast(unsigned short, h);
}

DEV float gelu_f(float x) {
  return 0.5f * x * (1.f + tanhf(0.7978845608028654f * (x + 0.044715f * x * x * x)));
}

// ---------------- weight transpose + fp32->bf16 convert: W[K,N] -> Wt[N,K] ----------------
__global__ __launch_bounds__(256) void wtrans_kernel(const float* __restrict__ W,
                                                     hbf* __restrict__ Wt, int K, int N) {
  __shared__ float tile[32][33];
  int k0 = blockIdx.x * 32, n0 = blockIdx.y * 32;
  int tx = threadIdx.x & 31, ty = threadIdx.x >> 5;  // ty in 0..7
  for (int r = ty; r < 32; r += 8) tile[r][tx] = W[(size_t)(k0 + r) * N + n0 + tx];
  __syncthreads();
  for (int r = ty; r < 32; r += 8)
    Wt[(size_t)(n0 + r) * K + k0 + tx] = __float2bfloat16(tile[tx][r]);
}

// ---------------- layernorm (fp32 in, bf16 out), one block per row, D=1024 ----------------
__global__ __launch_bounds__(256) void ln_kernel(const float* __restrict__ x,
                                                 const float* __restrict__ g,
                                                 const float* __restrict__ b,
                                                 hbf* __restrict__ y) {
  int row = blockIdx.x;
  int t = threadIdx.x;
  const float4 v = ((const float4*)(x + (size_t)row * Dm))[t];
  float s = v.x + v.y + v.z + v.w;
  float q = v.x * v.x + v.y * v.y + v.z * v.z + v.w * v.w;
#pragma unroll
  for (int off = 32; off > 0; off >>= 1) {
    s += __shfl_down(s, off);
    q += __shfl_down(q, off);
  }
  __shared__ float red[10];
  int wave = t >> 6, lane = t & 63;
  if (lane == 0) { red[wave] = s; red[4 + wave] = q; }
  __syncthreads();
  if (t == 0) {
    float ts = red[0] + red[1] + red[2] + red[3];
    float tq = red[4] + red[5] + red[6] + red[7];
    float mean = ts * (1.f / Dm);
    float var = tq * (1.f / Dm) - mean * mean;
    red[8] = mean;
    red[9] = rsqrtf(var + 1e-5f);
  }
  __syncthreads();
  float mean = red[8], inv = red[9];
  float4 gv = ((const float4*)g)[t];
  float4 bv = ((const float4*)b)[t];
  ushort4 o;
  o.x = f2bfu(gv.x * (v.x - mean) * inv + bv.x);
  o.y = f2bfu(gv.y * (v.y - mean) * inv + bv.y);
  o.z = f2bfu(gv.z * (v.z - mean) * inv + bv.z);
  o.w = f2bfu(gv.w * (v.w - mean) * inv + bv.w);
  ((ushort4*)(y + (size_t)row * Dm))[t] = o;
}

// ---------------- GEMM: C[M,N] = A[M,K](bf16) @ Bt[N,K]^T(bf16), 128x128 tile, BK=32 ------
// ACT: 0=none 1=gelu.  OUT_BF16: write bf16 else fp32.  res: fp32 residual (same shape as C)
template <int ACT, bool HAS_BIAS, bool HAS_RES, bool OUT_BF16>
__global__ __launch_bounds__(256, 2) void gemm_bt(const hbf* __restrict__ A,
                                                  const hbf* __restrict__ Bt,
                                                  void* __restrict__ Cv,
                                                  const float* __restrict__ bias,
                                                  const float* __restrict__ res,
                                                  int M, int N, int K) {
  __shared__ __align__(16) hbf As[128 * 32];
  __shared__ __align__(16) hbf Bs[128 * 32];
  const int tid = threadIdx.x;
  const int lane = tid & 63, wave = tid >> 6;
  const int wr = wave >> 1, wc = wave & 1;  // 2x2 waves, each 64x64 out
  const int lr = lane & 15, lg = lane >> 4;
  const int m0 = blockIdx.x * 128, n0 = blockIdx.y * 128;

  f32x4 acc[4][4] = {};

  for (int kk = 0; kk < K; kk += 32) {
#pragma unroll
    for (int j = 0; j < 2; ++j) {
      int idx = j * 256 + tid;
      int r = idx >> 2, c8 = (idx & 3) << 3;
      const hbf* ga = A + (size_t)(m0 + r) * K + kk + c8;
      const hbf* gb = Bt + (size_t)(n0 + r) * K + kk + c8;
      __builtin_amdgcn_global_load_lds((const __attribute__((address_space(1))) void*)ga,
                                       (__attribute__((address_space(3))) void*)(As + (size_t)idx * 8),
                                       16, 0, 0);
      __builtin_amdgcn_global_load_lds((const __attribute__((address_space(1))) void*)gb,
                                       (__attribute__((address_space(3))) void*)(Bs + (size_t)idx * 8),
                                       16, 0, 0);
    }
    __syncthreads();
    bf16x8 af[4], bfr[4];
#pragma unroll
    for (int m = 0; m < 4; ++m)
      af[m] = *(const bf16x8*)(As + (wr * 64 + m * 16 + lr) * 32 + lg * 8);
#pragma unroll
    for (int n = 0; n < 4; ++n)
      bfr[n] = *(const bf16x8*)(Bs + (wc * 64 + n * 16 + lr) * 32 + lg * 8);
#pragma unroll
    for (int m = 0; m < 4; ++m)
#pragma unroll
      for (int n = 0; n < 4; ++n)
        acc[m][n] = __builtin_amdgcn_mfma_f32_16x16x32_bf16(af[m], bfr[n], acc[m][n], 0, 0, 0);
    __syncthreads();
  }

#pragma unroll
  for (int m = 0; m < 4; ++m) {
    int row = m0 + wr * 64 + m * 16 + lg * 4;
#pragma unroll
    for (int n = 0; n < 4; ++n) {
      int col = n0 + wc * 64 + n * 16 + lr;
      float bvl = HAS_BIAS ? bias[col] : 0.f;
#pragma unroll
      for (int j = 0; j < 4; ++j) {
        float v = acc[m][n][j] + bvl;
        if (ACT == 1) v = gelu_f(v);
        if (HAS_RES) v += res[(size_t)(row + j) * N + col];
        if (OUT_BF16)
          ((hbf*)Cv)[(size_t)(row + j) * N + col] = __float2bfloat16(v);
        else
          ((float*)Cv)[(size_t)(row + j) * N + col] = v;
      }
    }
  }
}

// ---------------- per-head V transpose: v[b,s,h*64+d] -> vt[(b*H+h)*64+d, s] --------------
__global__ __launch_bounds__(256) void vtrans_kernel(const hbf* __restrict__ v,
                                                     hbf* __restrict__ vt) {
  __shared__ unsigned short tile[64][65];
  int bh = blockIdx.y, b = bh >> 4, hh = bh & 15;
  int s0 = blockIdx.x * 64;
  int d = threadIdx.x & 63, r0 = threadIdx.x >> 6;
#pragma unroll
  for (int i = 0; i < 16; ++i) {
    int r = r0 * 16 + i;
    tile[d][r] = __builtin_bit_cast(unsigned short,
                                    v[(size_t)(b * Ss + s0 + r) * Dm + hh * 64 + d]);
  }
  __syncthreads();
#pragma unroll
  for (int i = 0; i < 16; ++i) {
    int r = r0 * 16 + i;
    vt[(size_t)(bh * 64 + r) * Ss + s0 + d] = __builtin_bit_cast(hbf, tile[r][d]);
  }
}

// ---------------- causal flash attention -------------------------------------------------
// grid (S/64, B*H), 256 thr = 4 waves, each wave owns 16 q-rows. KV tile = 32.
__global__ __launch_bounds__(256, 2) void attn_kernel(const hbf* __restrict__ q,
                                                      const hbf* __restrict__ k,
                                                      const hbf* __restrict__ vt,
                                                      hbf* __restrict__ ctx) {
  __shared__ __align__(16) hbf p_lds[4][16][32];
  int bh = blockIdx.y;
  int b = bh >> 4, hh = bh & 15;
  int wave = threadIdx.x >> 6, lane = threadIdx.x & 63;
  int lr = lane & 15, lg = lane >> 4;
  int q0 = blockIdx.x * 64 + wave * 16;

  const hbf* qp = q + (size_t)(b * Ss + q0 + lr) * Dm + hh * 64 + lg * 8;
  bf16x8 aq0 = *(const bf16x8*)qp;
  bf16x8 aq1 = *(const bf16x8*)(qp + 32);

  f32x4 o[4] = {};
  float m_run[4], l_run[4];
#pragma unroll
  for (int r = 0; r < 4; ++r) { m_run[r] = -1e30f; l_run[r] = 0.f; }

  const int kv_end = q0 + 16;
  for (int k0 = 0; k0 < kv_end; k0 += 32) {
    f32x4 s[2] = {};
#pragma unroll
    for (int c = 0; c < 2; ++c) {
      const hbf* kp = k + (size_t)(b * Ss + k0 + c * 16 + lr) * Dm + hh * 64 + lg * 8;
      bf16x8 bk0 = *(const bf16x8*)kp;
      bf16x8 bk1 = *(const bf16x8*)(kp + 32);
      s[c] = __builtin_amdgcn_mfma_f32_16x16x32_bf16(aq0, bk0, s[c], 0, 0, 0);
      s[c] = __builtin_amdgcn_mfma_f32_16x16x32_bf16(aq1, bk1, s[c], 0, 0, 0);
    }
    float mx[4];
#pragma unroll
    for (int r = 0; r < 4; ++r) {
      int row = q0 + lg * 4 + r;
#pragma unroll
      for (int c = 0; c < 2; ++c) {
        float val = s[c][r] * 0.125f;
        int col = k0 + c * 16 + lr;
        if (col > row) val = -1e30f;
        s[c][r] = val;
      }
      mx[r] = fmaxf(s[0][r], s[1][r]);
    }
#pragma unroll
    for (int off = 1; off < 16; off <<= 1)
#pragma unroll
      for (int r = 0; r < 4; ++r) mx[r] = fmaxf(mx[r], __shfl_xor(mx[r], off));
    float rs[4];
#pragma unroll
    for (int r = 0; r < 4; ++r) {
      float mn = fmaxf(m_run[r], mx[r]);
      float sc = __expf(m_run[r] - mn);
      m_run[r] = mn;
      float p0 = __expf(s[0][r] - mn), p1 = __expf(s[1][r] - mn);
      s[0][r] = p0;
      s[1][r] = p1;
      rs[r] = p0 + p1;
      l_run[r] *= sc;
#pragma unroll
      for (int n = 0; n < 4; ++n) o[n][r] *= sc;
    }
#pragma unroll
    for (int off = 1; off < 16; off <<= 1)
#pragma unroll
      for (int r = 0; r < 4; ++r) rs[r] += __shfl_xor(rs[r], off);
#pragma unroll
    for (int r = 0; r < 4; ++r) l_run[r] += rs[r];

    // stage P (bf16) to per-wave LDS, then read A-fragments for PV
#pragma unroll
    for (int c = 0; c < 2; ++c)
#pragma unroll
      for (int r = 0; r < 4; ++r)
        p_lds[wave][lg * 4 + r][c * 16 + lr] = __float2bfloat16(s[c][r]);
    asm volatile("s_waitcnt lgkmcnt(0)" ::: "memory");
    bf16x8 pa = *(const bf16x8*)&p_lds[wave][lr][lg * 8];
#pragma unroll
    for (int n = 0; n < 4; ++n) {
      const hbf* vp = vt + (size_t)(bh * 64 + n * 16 + lr) * Ss + k0 + lg * 8;
      bf16x8 bv = *(const bf16x8*)vp;
      o[n] = __builtin_amdgcn_mfma_f32_16x16x32_bf16(pa, bv, o[n], 0, 0, 0);
    }
    asm volatile("s_waitcnt lgkmcnt(0)" ::: "memory");
  }

#pragma unroll
  for (int n = 0; n < 4; ++n)
#pragma unroll
    for (int r = 0; r < 4; ++r) {
      float val = o[n][r] / l_run[r];
      ctx[(size_t)(b * Ss + q0 + lg * 4 + r) * Dm + hh * 64 + n * 16 + lr] =
          __float2bfloat16(val);
    }
}

// -----------------------------------------------------------------------------------------
extern "C" void kernel_launch(void* const* d_in, const int* in_sizes, int n_in,
                              void* d_out, int out_size, void* d_ws, size_t ws_size,
                              hipStream_t stream) {
  const float* x  = (const float*)d_in[0];
  const float* Wq = (const float*)d_in[1];
  const float* Wk = (const float*)d_in[2];
  const float* Wv = (const float*)d_in[3];
  const float* Wo = (const float*)d_in[4];
  const float* bo = (const float*)d_in[5];
  const float* W1 = (const float*)d_in[6];
  const float* b1 = (const float*)d_in[7];
  const float* W2 = (const float*)d_in[8];
  const float* b2 = (const float*)d_in[9];
  const float* g1 = (const float*)d_in[10];
  const float* s1 = (const float*)d_in[11];
  const float* g2 = (const float*)d_in[12];
  const float* s2 = (const float*)d_in[13];
  float* out = (float*)d_out;

  char* ws = (char*)d_ws;
  constexpr size_t MB = 1024ull * 1024ull;
  hbf* wqT = (hbf*)(ws + 0 * MB);     // 2MB
  hbf* wkT = (hbf*)(ws + 2 * MB);     // 2MB
  hbf* wvT = (hbf*)(ws + 4 * MB);     // 2MB
  hbf* woT = (hbf*)(ws + 6 * MB);     // 2MB
  hbf* w1T = (hbf*)(ws + 8 * MB);     // 8MB
  hbf* w2T = (hbf*)(ws + 16 * MB);    // 8MB
  hbf* xln = (hbf*)(ws + 24 * MB);    // 16MB (reused: ctx, then y2)
  hbf* ctx = (hbf*)(ws + 24 * MB);
  hbf* y2  = (hbf*)(ws + 24 * MB);
  hbf* qb  = (hbf*)(ws + 40 * MB);    // 16MB
  hbf* kb  = (hbf*)(ws + 56 * MB);    // 16MB
  hbf* vb  = (hbf*)(ws + 72 * MB);    // 16MB
  hbf* vtb = (hbf*)(ws + 88 * MB);    // 16MB
  hbf* ff1 = (hbf*)(ws + 40 * MB);    // 64MB (over dead q/k/v/vt)
  float* hb = (float*)(ws + 104 * MB); // 32MB fp32
  (void)ws_size; (void)in_sizes; (void)n_in; (void)out_size;

  const int BS = Bb * Ss;  // 8192 rows

  // 1) weights -> bf16 transposed [N,K]
  wtrans_kernel<<<dim3(32, 32), 256, 0, stream>>>(Wq, wqT, Dm, Dm);
  wtrans_kernel<<<dim3(32, 32), 256, 0, stream>>>(Wk, wkT, Dm, Dm);
  wtrans_kernel<<<dim3(32, 32), 256, 0, stream>>>(Wv, wvT, Dm, Dm);
  wtrans_kernel<<<dim3(32, 32), 256, 0, stream>>>(Wo, woT, Dm, Dm);
  wtrans_kernel<<<dim3(32, 128), 256, 0, stream>>>(W1, w1T, Dm, DFm);
  wtrans_kernel<<<dim3(128, 32), 256, 0, stream>>>(W2, w2T, DFm, Dm);

  // 2) LN1
  ln_kernel<<<BS, 256, 0, stream>>>(x, g1, s1, xln);

  // 3) QKV projections
  gemm_bt<0, false, false, true><<<dim3(64, 8), 256, 0, stream>>>(xln, wqT, qb, nullptr, nullptr, BS, Dm, Dm);
  gemm_bt<0, false, false, true><<<dim3(64, 8), 256, 0, stream>>>(xln, wkT, kb, nullptr, nullptr, BS, Dm, Dm);
  gemm_bt<0, false, false, true><<<dim3(64, 8), 256, 0, stream>>>(xln, wvT, vb, nullptr, nullptr, BS, Dm, Dm);

  // 4) V transpose per head
  vtrans_kernel<<<dim3(Ss / 64, Bb * Hh), 256, 0, stream>>>(vb, vtb);

  // 5) flash attention
  attn_kernel<<<dim3(Ss / 64, Bb * Hh), 256, 0, stream>>>(qb, kb, vtb, ctx);

  // 6) output projection + bias + residual -> h (fp32)
  gemm_bt<0, true, true, false><<<dim3(64, 8), 256, 0, stream>>>(ctx, woT, hb, bo, x, BS, Dm, Dm);

  // 7) LN2
  ln_kernel<<<BS, 256, 0, stream>>>(hb, g2, s2, y2);

  // 8) FF1 + bias + GELU
  gemm_bt<1, true, false, true><<<dim3(64, 32), 256, 0, stream>>>(y2, w1T, ff1, b1, nullptr, BS, DFm, Dm);

  // 9) FF2 + bias + residual -> out (fp32)
  gemm_bt<0, true, true, false><<<dim3(64, 8), 256, 0, stream>>>(ff1, w2T, out, b2, hb, BS, Dm, DFm);
}

// Round 2
// 564.999 us; speedup vs baseline: 1.4111x; 1.4111x over previous
//
#include <hip/hip_runtime.h>
#include <hip/hip_bf16.h>

#define DEV __device__ __forceinline__

typedef __bf16 bf16x8 __attribute__((ext_vector_type(8)));
typedef float f32x4 __attribute__((ext_vector_type(4)));
typedef __hip_bfloat16 hbf;

constexpr int Dm = 1024;
constexpr int Hh = 16;
constexpr int Ss = 2048;
constexpr int Bb = 4;
constexpr int DFm = 4096;

DEV unsigned short f2bfu(float f) {
  hbf h = __float2bfloat16(f);
  return __builtin_bit_cast(unsigned short, h);
}

DEV float gelu_f(float x) {
  return 0.5f * x * (1.f + tanhf(0.7978845608028654f * (x + 0.044715f * x * x * x)));
}

// ---------------- weight transpose + fp32->bf16 convert: W[K,N] -> Wt[N,K] ----------------
__global__ __launch_bounds__(256) void wtrans_kernel(const float* __restrict__ W,
                                                     hbf* __restrict__ Wt, int K, int N) {
  __shared__ float tile[32][33];
  int k0 = blockIdx.x * 32, n0 = blockIdx.y * 32;
  int tx = threadIdx.x & 31, ty = threadIdx.x >> 5;  // ty in 0..7
  for (int r = ty; r < 32; r += 8) tile[r][tx] = W[(size_t)(k0 + r) * N + n0 + tx];
  __syncthreads();
  for (int r = ty; r < 32; r += 8)
    Wt[(size_t)(n0 + r) * K + k0 + tx] = __float2bfloat16(tile[tx][r]);
}

// ---------------- layernorm (fp32 in, bf16 out), one block per row, D=1024 ----------------
__global__ __launch_bounds__(256) void ln_kernel(const float* __restrict__ x,
                                                 const float* __restrict__ g,
                                                 const float* __restrict__ b,
                                                 hbf* __restrict__ y) {
  int row = blockIdx.x;
  int t = threadIdx.x;
  const float4 v = ((const float4*)(x + (size_t)row * Dm))[t];
  float s = v.x + v.y + v.z + v.w;
  float q = v.x * v.x + v.y * v.y + v.z * v.z + v.w * v.w;
#pragma unroll
  for (int off = 32; off > 0; off >>= 1) {
    s += __shfl_down(s, off);
    q += __shfl_down(q, off);
  }
  __shared__ float red[10];
  int wave = t >> 6, lane = t & 63;
  if (lane == 0) { red[wave] = s; red[4 + wave] = q; }
  __syncthreads();
  if (t == 0) {
    float ts = red[0] + red[1] + red[2] + red[3];
    float tq = red[4] + red[5] + red[6] + red[7];
    float mean = ts * (1.f / Dm);
    float var = tq * (1.f / Dm) - mean * mean;
    red[8] = mean;
    red[9] = rsqrtf(var + 1e-5f);
  }
  __syncthreads();
  float mean = red[8], inv = red[9];
  float4 gv = ((const float4*)g)[t];
  float4 bv = ((const float4*)b)[t];
  ushort4 o;
  o.x = f2bfu(gv.x * (v.x - mean) * inv + bv.x);
  o.y = f2bfu(gv.y * (v.y - mean) * inv + bv.y);
  o.z = f2bfu(gv.z * (v.z - mean) * inv + bv.z);
  o.w = f2bfu(gv.w * (v.w - mean) * inv + bv.w);
  ((ushort4*)(y + (size_t)row * Dm))[t] = o;
}

// ---------------- GEMM: C[M,N] = A[M,K](bf16) @ Bt[N,K]^T(bf16), 128x128 tile, BK=32 ------
template <int ACT, bool HAS_BIAS, bool HAS_RES, bool OUT_BF16>
__global__ __launch_bounds__(256, 2) void gemm_bt(const hbf* __restrict__ A,
                                                  const hbf* __restrict__ Bt,
                                                  void* __restrict__ Cv,
                                                  const float* __restrict__ bias,
                                                  const float* __restrict__ res,
                                                  int M, int N, int K) {
  __shared__ __align__(16) hbf As[128 * 32];
  __shared__ __align__(16) hbf Bs[128 * 32];
  const int tid = threadIdx.x;
  const int lane = tid & 63, wave = tid >> 6;
  const int wr = wave >> 1, wc = wave & 1;  // 2x2 waves, each 64x64 out
  const int lr = lane & 15, lg = lane >> 4;
  const int m0 = blockIdx.x * 128, n0 = blockIdx.y * 128;

  f32x4 acc[4][4] = {};

  for (int kk = 0; kk < K; kk += 32) {
#pragma unroll
    for (int j = 0; j < 2; ++j) {
      int idx = j * 256 + tid;
      int r = idx >> 2, c8 = (idx & 3) << 3;
      const hbf* ga = A + (size_t)(m0 + r) * K + kk + c8;
      const hbf* gb = Bt + (size_t)(n0 + r) * K + kk + c8;
      __builtin_amdgcn_global_load_lds((const __attribute__((address_space(1))) void*)ga,
                                       (__attribute__((address_space(3))) void*)(As + (size_t)idx * 8),
                                       16, 0, 0);
      __builtin_amdgcn_global_load_lds((const __attribute__((address_space(1))) void*)gb,
                                       (__attribute__((address_space(3))) void*)(Bs + (size_t)idx * 8),
                                       16, 0, 0);
    }
    __syncthreads();
    bf16x8 af[4], bfr[4];
#pragma unroll
    for (int m = 0; m < 4; ++m)
      af[m] = *(const bf16x8*)(As + (wr * 64 + m * 16 + lr) * 32 + lg * 8);
#pragma unroll
    for (int n = 0; n < 4; ++n)
      bfr[n] = *(const bf16x8*)(Bs + (wc * 64 + n * 16 + lr) * 32 + lg * 8);
#pragma unroll
    for (int m = 0; m < 4; ++m)
#pragma unroll
      for (int n = 0; n < 4; ++n)
        acc[m][n] = __builtin_amdgcn_mfma_f32_16x16x32_bf16(af[m], bfr[n], acc[m][n], 0, 0, 0);
    __syncthreads();
  }

#pragma unroll
  for (int m = 0; m < 4; ++m) {
    int row = m0 + wr * 64 + m * 16 + lg * 4;
#pragma unroll
    for (int n = 0; n < 4; ++n) {
      int col = n0 + wc * 64 + n * 16 + lr;
      float bvl = HAS_BIAS ? bias[col] : 0.f;
#pragma unroll
      for (int j = 0; j < 4; ++j) {
        float v = acc[m][n][j] + bvl;
        if (ACT == 1) v = gelu_f(v);
        if (HAS_RES) v += res[(size_t)(row + j) * N + col];
        if (OUT_BF16)
          ((hbf*)Cv)[(size_t)(row + j) * N + col] = __float2bfloat16(v);
        else
          ((float*)Cv)[(size_t)(row + j) * N + col] = v;
      }
    }
  }
}

// ---------------- per-head V transpose: v[b,s,h*64+d] -> vt[(b*H+h)*64+d, s] --------------
__global__ __launch_bounds__(256) void vtrans_kernel(const hbf* __restrict__ v,
                                                     hbf* __restrict__ vt) {
  __shared__ unsigned short tile[64][65];
  int bh = blockIdx.y, b = bh >> 4, hh = bh & 15;
  int s0 = blockIdx.x * 64;
  int d = threadIdx.x & 63, r0 = threadIdx.x >> 6;
#pragma unroll
  for (int i = 0; i < 16; ++i) {
    int r = r0 * 16 + i;
    tile[d][r] = __builtin_bit_cast(unsigned short,
                                    v[(size_t)(b * Ss + s0 + r) * Dm + hh * 64 + d]);
  }
  __syncthreads();
#pragma unroll
  for (int i = 0; i < 16; ++i) {
    int r = r0 * 16 + i;
    vt[(size_t)(bh * 64 + r) * Ss + s0 + d] = __builtin_bit_cast(hbf, tile[r][d]);
  }
}

// ---------------- causal flash attention, LDS-staged, double-buffered --------------------
// grid (S/128, B*H), 256 thr = 4 waves; wave w owns q rows [q0b+32w, q0b+32w+32).
// KV step = 64. K tile [64 k][64 d], V^T tile [64 d][64 k], both XOR-swizzled in LDS.
__global__ __launch_bounds__(256, 3) void attn_kernel(const hbf* __restrict__ q,
                                                      const hbf* __restrict__ k,
                                                      const hbf* __restrict__ vt,
                                                      hbf* __restrict__ ctx) {
  __shared__ __align__(16) hbf Ks[2][64 * 64];
  __shared__ __align__(16) hbf Vs[2][64 * 64];
  __shared__ __align__(16) hbf Ps[4][32 * 72];  // per-wave P, padded stride 72

  const int tid = threadIdx.x;
  const int wave = tid >> 6, lane = tid & 63;
  const int lr = lane & 15, lg = lane >> 4;
  const int bh = blockIdx.y, b = bh >> 4, hh = bh & 15;
  const int q0b = blockIdx.x * 128;
  const int q0w = q0b + wave * 32;

  // staging thread coords: 2 chunks of 16B per thread per tile (64 rows x 8 chunks)
  const int srow0 = tid >> 3, sch0 = tid & 7;
  const int srow1 = (256 + tid) >> 3, sch1 = sch0;  // idx+256 -> row+32, same chunk
  const int schg0 = sch0 ^ (srow0 & 7);
  const int schg1 = sch1 ^ (srow1 & 7);
  const hbf* kbase = k + (size_t)(b * Ss) * Dm + hh * 64;         // row stride Dm
  const hbf* vbase = vt + (size_t)(bh * 64) * Ss;                 // row stride Ss

  // Q fragments, pre-scaled by 0.125*log2(e) so scores are in exp2 units
  constexpr float QSCALE = 0.18033688011112042f;
  bf16x8 aq[2][2];
#pragma unroll
  for (int qt = 0; qt < 2; ++qt) {
    const hbf* qrow = q + (size_t)(b * Ss + q0w + qt * 16 + lr) * Dm + hh * 64;
#pragma unroll
    for (int ds = 0; ds < 2; ++ds) {
      bf16x8 t = *(const bf16x8*)(qrow + ds * 32 + lg * 8);
#pragma unroll
      for (int e = 0; e < 8; ++e) aq[qt][ds][e] = (__bf16)((float)t[e] * QSCALE);
    }
  }

  f32x4 o[2][4] = {};
  float m_run[2][4], l_run[2][4];
#pragma unroll
  for (int qt = 0; qt < 2; ++qt)
#pragma unroll
    for (int r = 0; r < 4; ++r) { m_run[qt][r] = -1e30f; l_run[qt][r] = 0.f; }

  const int nsteps = (q0b + 128) >> 6;
  const int my_end = q0w + 32;  // exclusive causal kv bound for this wave

  // prologue: stage tile 0 into buf 0
  {
    const hbf* kb0 = kbase;
    const hbf* vb0 = vbase;
    __builtin_amdgcn_global_load_lds((const __attribute__((address_space(1))) void*)(kb0 + (size_t)srow0 * Dm + schg0 * 8),
                                     (__attribute__((address_space(3))) void*)(&Ks[0][0] + tid * 8), 16, 0, 0);
    __builtin_amdgcn_global_load_lds((const __attribute__((address_space(1))) void*)(kb0 + (size_t)srow1 * Dm + schg1 * 8),
                                     (__attribute__((address_space(3))) void*)(&Ks[0][0] + (256 + tid) * 8), 16, 0, 0);
    __builtin_amdgcn_global_load_lds((const __attribute__((address_space(1))) void*)(vb0 + (size_t)srow0 * Ss + schg0 * 8),
                                     (__attribute__((address_space(3))) void*)(&Vs[0][0] + tid * 8), 16, 0, 0);
    __builtin_amdgcn_global_load_lds((const __attribute__((address_space(1))) void*)(vb0 + (size_t)srow1 * Ss + schg1 * 8),
                                     (__attribute__((address_space(3))) void*)(&Vs[0][0] + (256 + tid) * 8), 16, 0, 0);
  }
  asm volatile("s_waitcnt vmcnt(0)" ::: "memory");
  __syncthreads();

  int buf = 0;
  for (int it = 0; it < nsteps; ++it) {
    const int k0 = it << 6;
    // prefetch next tile into buf^1
    if (it + 1 < nsteps) {
      const hbf* kbn = kbase + (size_t)(k0 + 64) * Dm;
      const hbf* vbn = vbase + (k0 + 64);
      hbf* kd = &Ks[buf ^ 1][0];
      hbf* vd = &Vs[buf ^ 1][0];
      __builtin_amdgcn_global_load_lds((const __attribute__((address_space(1))) void*)(kbn + (size_t)srow0 * Dm + schg0 * 8),
                                       (__attribute__((address_space(3))) void*)(kd + tid * 8), 16, 0, 0);
      __builtin_amdgcn_global_load_lds((const __attribute__((address_space(1))) void*)(kbn + (size_t)srow1 * Dm + schg1 * 8),
                                       (__attribute__((address_space(3))) void*)(kd + (256 + tid) * 8), 16, 0, 0);
      __builtin_amdgcn_global_load_lds((const __attribute__((address_space(1))) void*)(vbn + (size_t)srow0 * Ss + schg0 * 8),
                                       (__attribute__((address_space(3))) void*)(vd + tid * 8), 16, 0, 0);
      __builtin_amdgcn_global_load_lds((const __attribute__((address_space(1))) void*)(vbn + (size_t)srow1 * Ss + schg1 * 8),
                                       (__attribute__((address_space(3))) void*)(vd + (256 + tid) * 8), 16, 0, 0);
    }

    if (k0 < my_end) {  // wave-uniform causal activity
      // ---- QK^T: s[qt][kc], 16 MFMA ----
      f32x4 s[2][4] = {};
      bf16x8 bk[4][2];
      const hbf* kt = &Ks[buf][0];
#pragma unroll
      for (int kc = 0; kc < 4; ++kc)
#pragma unroll
        for (int ds = 0; ds < 2; ++ds)
          bk[kc][ds] = *(const bf16x8*)(kt + (kc * 16 + lr) * 64 + 8 * ((ds * 4 + lg) ^ (lr & 7)));
#pragma unroll
      for (int qt = 0; qt < 2; ++qt)
#pragma unroll
        for (int kc = 0; kc < 4; ++kc)
#pragma unroll
          for (int ds = 0; ds < 2; ++ds)
            s[qt][kc] = __builtin_amdgcn_mfma_f32_16x16x32_bf16(aq[qt][ds], bk[kc][ds], s[qt][kc], 0, 0, 0);

      // ---- causal mask (diagonal tiles only) ----
      if (k0 + 63 > q0w) {
#pragma unroll
        for (int qt = 0; qt < 2; ++qt)
#pragma unroll
          for (int kc = 0; kc < 4; ++kc) {
            int col = k0 + kc * 16 + lr;
#pragma unroll
            for (int r = 0; r < 4; ++r) {
              int row = q0w + qt * 16 + lg * 4 + r;
              if (col > row) s[qt][kc][r] = -3e38f;
            }
          }
      }

      // ---- row max ----
      float mx[2][4];
#pragma unroll
      for (int qt = 0; qt < 2; ++qt)
#pragma unroll
        for (int r = 0; r < 4; ++r)
          mx[qt][r] = fmaxf(fmaxf(s[qt][0][r], s[qt][1][r]), fmaxf(s[qt][2][r], s[qt][3][r]));
#pragma unroll
      for (int off = 1; off < 16; off <<= 1)
#pragma unroll
        for (int qt = 0; qt < 2; ++qt)
#pragma unroll
          for (int r = 0; r < 4; ++r) mx[qt][r] = fmaxf(mx[qt][r], __shfl_xor(mx[qt][r], off));

      // ---- defer-max (THR = 8 nats = 11.54 in exp2 units) ----
      float growth = -1e30f;
#pragma unroll
      for (int qt = 0; qt < 2; ++qt)
#pragma unroll
        for (int r = 0; r < 4; ++r) growth = fmaxf(growth, mx[qt][r] - m_run[qt][r]);
      if (!__all(growth <= 11.541560327111707f)) {
#pragma unroll
        for (int qt = 0; qt < 2; ++qt)
#pragma unroll
          for (int r = 0; r < 4; ++r) {
            float mn = fmaxf(m_run[qt][r], mx[qt][r]);
            float sc = exp2f(m_run[qt][r] - mn);
            m_run[qt][r] = mn;
            l_run[qt][r] *= sc;
#pragma unroll
            for (int n = 0; n < 4; ++n) o[qt][n][r] *= sc;
          }
      }

      // ---- P = exp2(s - m), row sum ----
      float rs[2][4] = {};
#pragma unroll
      for (int qt = 0; qt < 2; ++qt)
#pragma unroll
        for (int kc = 0; kc < 4; ++kc)
#pragma unroll
          for (int r = 0; r < 4; ++r) {
            float p = exp2f(s[qt][kc][r] - m_run[qt][r]);
            s[qt][kc][r] = p;
            rs[qt][r] += p;
          }
#pragma unroll
      for (int off = 1; off < 16; off <<= 1)
#pragma unroll
        for (int qt = 0; qt < 2; ++qt)
#pragma unroll
          for (int r = 0; r < 4; ++r) rs[qt][r] += __shfl_xor(rs[qt][r], off);
#pragma unroll
      for (int qt = 0; qt < 2; ++qt)
#pragma unroll
        for (int r = 0; r < 4; ++r) l_run[qt][r] += rs[qt][r];

      // ---- stage P to per-wave LDS (bf16), padded stride 72 ----
      hbf* pw = &Ps[wave][0];
#pragma unroll
      for (int qt = 0; qt < 2; ++qt)
#pragma unroll
        for (int kc = 0; kc < 4; ++kc)
#pragma unroll
          for (int r = 0; r < 4; ++r)
            pw[(qt * 16 + lg * 4 + r) * 72 + kc * 16 + lr] = __float2bfloat16(s[qt][kc][r]);
      asm volatile("s_waitcnt lgkmcnt(0)" ::: "memory");
      __builtin_amdgcn_sched_barrier(0);

      // ---- PV: 16 MFMA ----
      bf16x8 pa[2][2];
#pragma unroll
      for (int qt = 0; qt < 2; ++qt)
#pragma unroll
        for (int ks = 0; ks < 2; ++ks)
          pa[qt][ks] = *(const bf16x8*)(pw + (qt * 16 + lr) * 72 + ks * 32 + lg * 8);
      const hbf* vtile = &Vs[buf][0];
#pragma unroll
      for (int n = 0; n < 4; ++n)
#pragma unroll
        for (int ks = 0; ks < 2; ++ks) {
          bf16x8 bv = *(const bf16x8*)(vtile + (n * 16 + lr) * 64 + 8 * ((ks * 4 + lg) ^ (lr & 7)));
#pragma unroll
          for (int qt = 0; qt < 2; ++qt)
            o[qt][n] = __builtin_amdgcn_mfma_f32_16x16x32_bf16(pa[qt][ks], bv, o[qt][n], 0, 0, 0);
        }
    }

    asm volatile("s_waitcnt vmcnt(0)" ::: "memory");
    __syncthreads();
    buf ^= 1;
  }

  // ---- epilogue ----
#pragma unroll
  for (int qt = 0; qt < 2; ++qt)
#pragma unroll
    for (int n = 0; n < 4; ++n)
#pragma unroll
      for (int r = 0; r < 4; ++r) {
        float val = o[qt][n][r] / l_run[qt][r];
        ctx[(size_t)(b * Ss + q0w + qt * 16 + lg * 4 + r) * Dm + hh * 64 + n * 16 + lr] =
            __float2bfloat16(val);
      }
}

// -----------------------------------------------------------------------------------------
extern "C" void kernel_launch(void* const* d_in, const int* in_sizes, int n_in,
                              void* d_out, int out_size, void* d_ws, size_t ws_size,
                              hipStream_t stream) {
  const float* x  = (const float*)d_in[0];
  const float* Wq = (const float*)d_in[1];
  const float* Wk = (const float*)d_in[2];
  const float* Wv = (const float*)d_in[3];
  const float* Wo = (const float*)d_in[4];
  const float* bo = (const float*)d_in[5];
  const float* W1 = (const float*)d_in[6];
  const float* b1 = (const float*)d_in[7];
  const float* W2 = (const float*)d_in[8];
  const float* b2 = (const float*)d_in[9];
  const float* g1 = (const float*)d_in[10];
  const float* s1 = (const float*)d_in[11];
  const float* g2 = (const float*)d_in[12];
  const float* s2 = (const float*)d_in[13];
  float* out = (float*)d_out;

  char* ws = (char*)d_ws;
  constexpr size_t MB = 1024ull * 1024ull;
  hbf* wqT = (hbf*)(ws + 0 * MB);     // 2MB
  hbf* wkT = (hbf*)(ws + 2 * MB);     // 2MB
  hbf* wvT = (hbf*)(ws + 4 * MB);     // 2MB
  hbf* woT = (hbf*)(ws + 6 * MB);     // 2MB
  hbf* w1T = (hbf*)(ws + 8 * MB);     // 8MB
  hbf* w2T = (hbf*)(ws + 16 * MB);    // 8MB
  hbf* xln = (hbf*)(ws + 24 * MB);    // 16MB (reused: ctx, then y2)
  hbf* ctx = (hbf*)(ws + 24 * MB);
  hbf* y2  = (hbf*)(ws + 24 * MB);
  hbf* qb  = (hbf*)(ws + 40 * MB);    // 16MB
  hbf* kb  = (hbf*)(ws + 56 * MB);    // 16MB
  hbf* vb  = (hbf*)(ws + 72 * MB);    // 16MB
  hbf* vtb = (hbf*)(ws + 88 * MB);    // 16MB
  hbf* ff1 = (hbf*)(ws + 40 * MB);    // 64MB (over dead q/k/v/vt)
  float* hb = (float*)(ws + 104 * MB); // 32MB fp32
  (void)ws_size; (void)in_sizes; (void)n_in; (void)out_size;

  const int BS = Bb * Ss;  // 8192 rows

  // 1) weights -> bf16 transposed [N,K]
  wtrans_kernel<<<dim3(32, 32), 256, 0, stream>>>(Wq, wqT, Dm, Dm);
  wtrans_kernel<<<dim3(32, 32), 256, 0, stream>>>(Wk, wkT, Dm, Dm);
  wtrans_kernel<<<dim3(32, 32), 256, 0, stream>>>(Wv, wvT, Dm, Dm);
  wtrans_kernel<<<dim3(32, 32), 256, 0, stream>>>(Wo, woT, Dm, Dm);
  wtrans_kernel<<<dim3(32, 128), 256, 0, stream>>>(W1, w1T, Dm, DFm);
  wtrans_kernel<<<dim3(128, 32), 256, 0, stream>>>(W2, w2T, DFm, Dm);

  // 2) LN1
  ln_kernel<<<BS, 256, 0, stream>>>(x, g1, s1, xln);

  // 3) QKV projections
  gemm_bt<0, false, false, true><<<dim3(64, 8), 256, 0, stream>>>(xln, wqT, qb, nullptr, nullptr, BS, Dm, Dm);
  gemm_bt<0, false, false, true><<<dim3(64, 8), 256, 0, stream>>>(xln, wkT, kb, nullptr, nullptr, BS, Dm, Dm);
  gemm_bt<0, false, false, true><<<dim3(64, 8), 256, 0, stream>>>(xln, wvT, vb, nullptr, nullptr, BS, Dm, Dm);

  // 4) V transpose per head
  vtrans_kernel<<<dim3(Ss / 64, Bb * Hh), 256, 0, stream>>>(vb, vtb);

  // 5) flash attention (LDS-staged, double-buffered, swizzled)
  attn_kernel<<<dim3(Ss / 128, Bb * Hh), 256, 0, stream>>>(qb, kb, vtb, ctx);

  // 6) output projection + bias + residual -> h (fp32)
  gemm_bt<0, true, true, false><<<dim3(64, 8), 256, 0, stream>>>(ctx, woT, hb, bo, x, BS, Dm, Dm);

  // 7) LN2
  ln_kernel<<<BS, 256, 0, stream>>>(hb, g2, s2, y2);

  // 8) FF1 + bias + GELU
  gemm_bt<1, true, false, true><<<dim3(64, 32), 256, 0, stream>>>(y2, w1T, ff1, b1, nullptr, BS, DFm, Dm);

  // 9) FF2 + bias + residual -> out (fp32)
  gemm_bt<0, true, true, false><<<dim3(64, 8), 256, 0, stream>>>(ff1, w2T, out, b2, hb, BS, Dm, DFm);
}

// Round 3
// 423.890 us; speedup vs baseline: 1.8809x; 1.3329x over previous
//
#include <hip/hip_runtime.h>
#include <hip/hip_bf16.h>

#define DEV __device__ __forceinline__

typedef __bf16 bf16x8 __attribute__((ext_vector_type(8)));
typedef __bf16 bf16x2v __attribute__((ext_vector_type(2)));
typedef float f32x4 __attribute__((ext_vector_type(4)));
typedef float f32x16 __attribute__((ext_vector_type(16)));
typedef unsigned int u32;
typedef unsigned int u32x4 __attribute__((ext_vector_type(4)));
typedef __hip_bfloat16 hbf;

constexpr int Dm = 1024;
constexpr int Hh = 16;
constexpr int Ss = 2048;
constexpr int Bb = 4;
constexpr int DFm = 4096;
constexpr int LDQ = 3072;  // fused qkv row stride

DEV unsigned short f2bfu(float f) {
  hbf h = __float2bfloat16(f);
  return __builtin_bit_cast(unsigned short, h);
}

DEV u32 pkbf(float x, float y) {
  bf16x2v v = {(__bf16)x, (__bf16)y};
  return __builtin_bit_cast(u32, v);
}

DEV float gelu_f(float x) {
  return 0.5f * x * (1.f + tanhf(0.7978845608028654f * (x + 0.044715f * x * x * x)));
}

#define GLDS(src, dst)                                                                     \
  __builtin_amdgcn_global_load_lds((const __attribute__((address_space(1))) void*)(src),   \
                                   (__attribute__((address_space(3))) void*)(dst), 16, 0, 0)

// ---------------- weight transpose + fp32->bf16 convert: W[K,N] -> Wt[N,K] ----------------
__global__ __launch_bounds__(256) void wtrans_kernel(const float* __restrict__ W,
                                                     hbf* __restrict__ Wt, int K, int N) {
  __shared__ float tile[32][33];
  int k0 = blockIdx.x * 32, n0 = blockIdx.y * 32;
  int tx = threadIdx.x & 31, ty = threadIdx.x >> 5;
  for (int r = ty; r < 32; r += 8) tile[r][tx] = W[(size_t)(k0 + r) * N + n0 + tx];
  __syncthreads();
  for (int r = ty; r < 32; r += 8)
    Wt[(size_t)(n0 + r) * K + k0 + tx] = __float2bfloat16(tile[tx][r]);
}

// ---------------- layernorm (fp32 in, bf16 out), one block per row, D=1024 ----------------
__global__ __launch_bounds__(256) void ln_kernel(const float* __restrict__ x,
                                                 const float* __restrict__ g,
                                                 const float* __restrict__ b,
                                                 hbf* __restrict__ y) {
  int row = blockIdx.x;
  int t = threadIdx.x;
  const float4 v = ((const float4*)(x + (size_t)row * Dm))[t];
  float s = v.x + v.y + v.z + v.w;
  float q = v.x * v.x + v.y * v.y + v.z * v.z + v.w * v.w;
#pragma unroll
  for (int off = 32; off > 0; off >>= 1) {
    s += __shfl_down(s, off);
    q += __shfl_down(q, off);
  }
  __shared__ float red[10];
  int wave = t >> 6, lane = t & 63;
  if (lane == 0) { red[wave] = s; red[4 + wave] = q; }
  __syncthreads();
  if (t == 0) {
    float ts = red[0] + red[1] + red[2] + red[3];
    float tq = red[4] + red[5] + red[6] + red[7];
    float mean = ts * (1.f / Dm);
    float var = tq * (1.f / Dm) - mean * mean;
    red[8] = mean;
    red[9] = rsqrtf(var + 1e-5f);
  }
  __syncthreads();
  float mean = red[8], inv = red[9];
  float4 gv = ((const float4*)g)[t];
  float4 bv = ((const float4*)b)[t];
  ushort4 o;
  o.x = f2bfu(gv.x * (v.x - mean) * inv + bv.x);
  o.y = f2bfu(gv.y * (v.y - mean) * inv + bv.y);
  o.z = f2bfu(gv.z * (v.z - mean) * inv + bv.z);
  o.w = f2bfu(gv.w * (v.w - mean) * inv + bv.w);
  ((ushort4*)(y + (size_t)row * Dm))[t] = o;
}

// ---------------- GEMM: C[M,N] = A[M,K](bf16) @ Bt[N,K]^T(bf16), 128x128 tile, BK=32 ------
template <int ACT, bool HAS_BIAS, bool HAS_RES, bool OUT_BF16>
__global__ __launch_bounds__(256, 2) void gemm_bt(const hbf* __restrict__ A,
                                                  const hbf* __restrict__ Bt,
                                                  void* __restrict__ Cv,
                                                  const float* __restrict__ bias,
                                                  const float* __restrict__ res,
                                                  int M, int N, int K) {
  __shared__ __align__(16) hbf As[128 * 32];
  __shared__ __align__(16) hbf Bs[128 * 32];
  const int tid = threadIdx.x;
  const int lane = tid & 63, wave = tid >> 6;
  const int wr = wave >> 1, wc = wave & 1;
  const int lr = lane & 15, lg = lane >> 4;
  const int m0 = blockIdx.x * 128, n0 = blockIdx.y * 128;

  f32x4 acc[4][4] = {};

  for (int kk = 0; kk < K; kk += 32) {
#pragma unroll
    for (int j = 0; j < 2; ++j) {
      int idx = j * 256 + tid;
      int r = idx >> 2, c8 = (idx & 3) << 3;
      const hbf* ga = A + (size_t)(m0 + r) * K + kk + c8;
      const hbf* gb = Bt + (size_t)(n0 + r) * K + kk + c8;
      GLDS(ga, As + (size_t)idx * 8);
      GLDS(gb, Bs + (size_t)idx * 8);
    }
    __syncthreads();
    bf16x8 af[4], bfr[4];
#pragma unroll
    for (int m = 0; m < 4; ++m)
      af[m] = *(const bf16x8*)(As + (wr * 64 + m * 16 + lr) * 32 + lg * 8);
#pragma unroll
    for (int n = 0; n < 4; ++n)
      bfr[n] = *(const bf16x8*)(Bs + (wc * 64 + n * 16 + lr) * 32 + lg * 8);
#pragma unroll
    for (int m = 0; m < 4; ++m)
#pragma unroll
      for (int n = 0; n < 4; ++n)
        acc[m][n] = __builtin_amdgcn_mfma_f32_16x16x32_bf16(af[m], bfr[n], acc[m][n], 0, 0, 0);
    __syncthreads();
  }

#pragma unroll
  for (int m = 0; m < 4; ++m) {
    int row = m0 + wr * 64 + m * 16 + lg * 4;
#pragma unroll
    for (int n = 0; n < 4; ++n) {
      int col = n0 + wc * 64 + n * 16 + lr;
      float bvl = HAS_BIAS ? bias[col] : 0.f;
#pragma unroll
      for (int j = 0; j < 4; ++j) {
        float v = acc[m][n][j] + bvl;
        if (ACT == 1) v = gelu_f(v);
        if (HAS_RES) v += res[(size_t)(row + j) * N + col];
        if (OUT_BF16)
          ((hbf*)Cv)[(size_t)(row + j) * N + col] = __float2bfloat16(v);
        else
          ((float*)Cv)[(size_t)(row + j) * N + col] = v;
      }
    }
  }
}

// ---------------- per-head V transpose: qkv[b,s,2048+h*64+d] -> vt[(b*H+h)*64+d, s] -------
__global__ __launch_bounds__(256) void vtrans_kernel(const hbf* __restrict__ qkv,
                                                     hbf* __restrict__ vt) {
  __shared__ unsigned short tile[64][65];
  int bh = blockIdx.y, b = bh >> 4, hh = bh & 15;
  int s0 = blockIdx.x * 64;
  int d = threadIdx.x & 63, r0 = threadIdx.x >> 6;
#pragma unroll
  for (int i = 0; i < 16; ++i) {
    int r = r0 * 16 + i;
    tile[d][r] = __builtin_bit_cast(unsigned short,
                                    qkv[(size_t)(b * Ss + s0 + r) * LDQ + 2048 + hh * 64 + d]);
  }
  __syncthreads();
#pragma unroll
  for (int i = 0; i < 16; ++i) {
    int r = r0 * 16 + i;
    vt[(size_t)(bh * 64 + r) * Ss + s0 + d] = __builtin_bit_cast(hbf, tile[r][d]);
  }
}

// ---------------- causal flash attention, swapped QK^T, in-register softmax ---------------
// 256 thr = 4 waves, QBLK=32/wave (block covers 128 q-rows), KVB=64.
// S^T = mfma32x32x16(K,Q): lane owns q=lane&31, 32 k-values in regs -> in-lane softmax.
// O^T = mfma32x32x16(V^T,P): stats stay lane-local.
__global__ __launch_bounds__(256, 3) void attn_kernel(const hbf* __restrict__ qkv,
                                                      const hbf* __restrict__ vt,
                                                      hbf* __restrict__ ctx) {
  __shared__ __align__(16) hbf Ks[2][64 * 64];
  __shared__ __align__(16) hbf Vs[2][64 * 64];

  const int tid = threadIdx.x;
  const int wave = tid >> 6, lane = tid & 63;
  const int l31 = lane & 31, hi = lane >> 5;

  // balanced grid remap: heavy tiles first; CU pairs (16-j)+(16-j)+(j+1)+(j+1)=const
  const int gi = blockIdx.x;
  const int g = gi >> 9, rr_ = gi & 511;
  const int bh = rr_ >> 3, j = rr_ & 7;
  const int bx = g ? j : 15 - j;
  const int b = bh >> 4, hh = bh & 15;
  const int q0b = bx * 128;
  const int q0w = q0b + wave * 32;
  const int nsteps = (q0b + 128) >> 6;
  const int my_steps = (q0w + 95) >> 6;

  // Q fragments (pre-scaled into exp2 units): qf[ds] = Q[q0w+l31][ds*16 + hi*8 + e]
  constexpr float QSCALE = 0.18033688011112042f;  // 0.125 * log2(e)
  bf16x8 qf[4];
  {
    const hbf* qrow = qkv + (size_t)(b * Ss + q0w + l31) * LDQ + hh * 64 + hi * 8;
#pragma unroll
    for (int ds = 0; ds < 4; ++ds) {
      bf16x8 t = *(const bf16x8*)(qrow + ds * 16);
#pragma unroll
      for (int e = 0; e < 8; ++e) qf[ds][e] = (__bf16)((float)t[e] * QSCALE);
    }
  }

  // staging coords: thread handles 16B chunks tid and tid+256 of each 8KB tile
  const hbf* kbase = qkv + 2048 / 2 + (size_t)(b * Ss) * LDQ + hh * 64;  // +1024 = K block
  const hbf* vbase = vt + (size_t)(bh * 64) * Ss;
  const int i0 = tid, i1 = tid + 256;
  const int r0 = i0 >> 3, s0c = (i0 & 7), r1 = i1 >> 3, s1c = (i1 & 7);
  const int c0 = 8 * (s0c ^ (r0 & 7)), c1 = 8 * (s1c ^ (r1 & 7));

  f32x16 ot[2] = {};
  float m_run = -1e30f, l_run = 0.f;

  // prologue: stage tile 0 into buf 0
  {
    hbf* kd = &Ks[0][0];
    hbf* vd = &Vs[0][0];
    GLDS(kbase + (size_t)r0 * LDQ + c0, kd + i0 * 8);
    GLDS(kbase + (size_t)r1 * LDQ + c1, kd + i1 * 8);
    GLDS(vbase + (size_t)r0 * Ss + c0, vd + i0 * 8);
    GLDS(vbase + (size_t)r1 * Ss + c1, vd + i1 * 8);
  }
  __syncthreads();

  int buf = 0;
  for (int it = 0; it < nsteps; ++it) {
    const int k0 = it << 6;
    if (it + 1 < nsteps) {
      hbf* kd = &Ks[buf ^ 1][0];
      hbf* vd = &Vs[buf ^ 1][0];
      GLDS(kbase + (size_t)(k0 + 64 + r0) * LDQ + c0, kd + i0 * 8);
      GLDS(kbase + (size_t)(k0 + 64 + r1) * LDQ + c1, kd + i1 * 8);
      GLDS(vbase + (size_t)r0 * Ss + k0 + 64 + c0, vd + i0 * 8);
      GLDS(vbase + (size_t)r1 * Ss + k0 + 64 + c1, vd + i1 * 8);
    }

    if (it < my_steps) {
      // ---- S^T[k=64][q=32]: 8 MFMA ----
      const hbf* kt = &Ks[buf][0];
      f32x16 st[2] = {};
#pragma unroll
      for (int c = 0; c < 2; ++c) {
        const int krow = l31 + 32 * c;
        const int kr7 = krow & 7;
#pragma unroll
        for (int ds = 0; ds < 4; ++ds) {
          bf16x8 kf = *(const bf16x8*)(kt + krow * 64 + 8 * ((ds * 2 + hi) ^ kr7));
          st[c] = __builtin_amdgcn_mfma_f32_32x32x16_bf16(kf, qf[ds], st[c], 0, 0, 0);
        }
      }

      // ---- causal mask (last active step only) ----
      if (it == my_steps - 1) {
        const int qg = q0w + l31;
#pragma unroll
        for (int c = 0; c < 2; ++c)
#pragma unroll
          for (int rg = 0; rg < 16; ++rg) {
            int kg = k0 + c * 32 + (rg & 3) + 8 * (rg >> 2) + 4 * hi;
            if (kg > qg) st[c][rg] = -3e38f;
          }
      }

      // ---- in-lane softmax (q = l31, partner lane l31+32 holds other 32 k) ----
      float mx = -3e38f;
#pragma unroll
      for (int c = 0; c < 2; ++c)
#pragma unroll
        for (int rg = 0; rg < 16; ++rg) mx = fmaxf(mx, st[c][rg]);
      mx = fmaxf(mx, __shfl_xor(mx, 32));
      if (!__all(mx - m_run <= 11.541560327111707f)) {  // defer-max THR=8 nats
        float mn = fmaxf(m_run, mx);
        float sc = exp2f(m_run - mn);
        m_run = mn;
        l_run *= sc;
#pragma unroll
        for (int dc = 0; dc < 2; ++dc)
#pragma unroll
          for (int rg = 0; rg < 16; ++rg) ot[dc][rg] *= sc;
      }
      float rs = 0.f;
#pragma unroll
      for (int c = 0; c < 2; ++c)
#pragma unroll
        for (int rg = 0; rg < 16; ++rg) {
          float p = exp2f(st[c][rg] - m_run);
          st[c][rg] = p;
          rs += p;
        }
      rs += __shfl_xor(rs, 32);
      l_run += rs;

      // ---- repack P^T -> B-fragments in-register (cvt_pk + half-swap) ----
      bf16x8 pf[2][2];
#pragma unroll
      for (int c = 0; c < 2; ++c)
#pragma unroll
        for (int ks = 0; ks < 2; ++ks) {
          const int rb = ks * 8;
          u32 a0 = pkbf(st[c][rb + 0], st[c][rb + 1]);
          u32 a1 = pkbf(st[c][rb + 2], st[c][rb + 3]);
          u32 b0 = pkbf(st[c][rb + 4], st[c][rb + 5]);
          u32 b1 = pkbf(st[c][rb + 6], st[c][rb + 7]);
          u32 pa0 = __shfl_xor(a0, 32), pa1 = __shfl_xor(a1, 32);
          u32 pb0 = __shfl_xor(b0, 32), pb1 = __shfl_xor(b1, 32);
          u32x4 f;
          f.x = hi ? pb0 : a0;
          f.y = hi ? pb1 : a1;
          f.z = hi ? b0 : pa0;
          f.w = hi ? b1 : pa1;
          pf[c][ks] = __builtin_bit_cast(bf16x8, f);
        }

      // ---- O^T += V^T · P : 8 MFMA ----
      const hbf* vtl = &Vs[buf][0];
#pragma unroll
      for (int dc = 0; dc < 2; ++dc) {
        const int vrow = l31 + 32 * dc;
        const int vr7 = vrow & 7;
#pragma unroll
        for (int c = 0; c < 2; ++c)
#pragma unroll
          for (int ks = 0; ks < 2; ++ks) {
            bf16x8 vf = *(const bf16x8*)(vtl + vrow * 64 + 8 * ((c * 4 + ks * 2 + hi) ^ vr7));
            ot[dc] = __builtin_amdgcn_mfma_f32_32x32x16_bf16(vf, pf[c][ks], ot[dc], 0, 0, 0);
          }
      }
    }

    __syncthreads();
    buf ^= 1;
  }

  // ---- epilogue: ctx[q][d], d = dc*32 + 8*rg + 4*hi + j ----
  const float inv = 1.f / l_run;
  hbf* crow = ctx + (size_t)(b * Ss + q0w + l31) * Dm + hh * 64;
#pragma unroll
  for (int dc = 0; dc < 2; ++dc)
#pragma unroll
    for (int rg = 0; rg < 4; ++rg) {
      ushort4 w;
      w.x = f2bfu(ot[dc][rg * 4 + 0] * inv);
      w.y = f2bfu(ot[dc][rg * 4 + 1] * inv);
      w.z = f2bfu(ot[dc][rg * 4 + 2] * inv);
      w.w = f2bfu(ot[dc][rg * 4 + 3] * inv);
      *(ushort4*)(crow + dc * 32 + rg * 8 + hi * 4) = w;
    }
}

// -----------------------------------------------------------------------------------------
extern "C" void kernel_launch(void* const* d_in, const int* in_sizes, int n_in,
                              void* d_out, int out_size, void* d_ws, size_t ws_size,
                              hipStream_t stream) {
  const float* x  = (const float*)d_in[0];
  const float* Wq = (const float*)d_in[1];
  const float* Wk = (const float*)d_in[2];
  const float* Wv = (const float*)d_in[3];
  const float* Wo = (const float*)d_in[4];
  const float* bo = (const float*)d_in[5];
  const float* W1 = (const float*)d_in[6];
  const float* b1 = (const float*)d_in[7];
  const float* W2 = (const float*)d_in[8];
  const float* b2 = (const float*)d_in[9];
  const float* g1 = (const float*)d_in[10];
  const float* s1 = (const float*)d_in[11];
  const float* g2 = (const float*)d_in[12];
  const float* s2 = (const float*)d_in[13];
  float* out = (float*)d_out;

  char* ws = (char*)d_ws;
  constexpr size_t MB = 1024ull * 1024ull;
  hbf* wqkvT = (hbf*)(ws + 0 * MB);    // 6MB [3072][1024]
  hbf* woT   = (hbf*)(ws + 6 * MB);    // 2MB
  hbf* w1T   = (hbf*)(ws + 8 * MB);    // 8MB
  hbf* w2T   = (hbf*)(ws + 16 * MB);   // 8MB
  hbf* xln   = (hbf*)(ws + 24 * MB);   // 16MB (reused: ctx, then y2)
  hbf* ctx   = (hbf*)(ws + 24 * MB);
  hbf* y2    = (hbf*)(ws + 24 * MB);
  hbf* qkvb  = (hbf*)(ws + 40 * MB);   // 48MB [8192][3072]
  hbf* vtb   = (hbf*)(ws + 88 * MB);   // 16MB
  hbf* ff1   = (hbf*)(ws + 40 * MB);   // 64MB (over dead qkv/vt)
  float* hb  = (float*)(ws + 104 * MB); // 32MB fp32
  (void)ws_size; (void)in_sizes; (void)n_in; (void)out_size;

  const int BS = Bb * Ss;  // 8192 rows

  // 1) weights -> bf16 transposed [N,K]; QKV packed into one [3072][1024]
  wtrans_kernel<<<dim3(32, 32), 256, 0, stream>>>(Wq, wqkvT, Dm, Dm);
  wtrans_kernel<<<dim3(32, 32), 256, 0, stream>>>(Wk, wqkvT + 1024 * 1024, Dm, Dm);
  wtrans_kernel<<<dim3(32, 32), 256, 0, stream>>>(Wv, wqkvT + 2 * 1024 * 1024, Dm, Dm);
  wtrans_kernel<<<dim3(32, 32), 256, 0, stream>>>(Wo, woT, Dm, Dm);
  wtrans_kernel<<<dim3(32, 128), 256, 0, stream>>>(W1, w1T, Dm, DFm);
  wtrans_kernel<<<dim3(128, 32), 256, 0, stream>>>(W2, w2T, DFm, Dm);

  // 2) LN1
  ln_kernel<<<BS, 256, 0, stream>>>(x, g1, s1, xln);

  // 3) fused QKV projection: [8192,1024] @ [1024,3072]
  gemm_bt<0, false, false, true><<<dim3(64, 24), 256, 0, stream>>>(xln, wqkvT, qkvb, nullptr, nullptr, BS, LDQ, Dm);

  // 4) V transpose per head
  vtrans_kernel<<<dim3(Ss / 64, Bb * Hh), 256, 0, stream>>>(qkvb, vtb);

  // 5) flash attention (swapped QK^T, in-register softmax)
  attn_kernel<<<dim3(1024), 256, 0, stream>>>(qkvb, vtb, ctx);

  // 6) output projection + bias + residual -> h (fp32)
  gemm_bt<0, true, true, false><<<dim3(64, 8), 256, 0, stream>>>(ctx, woT, hb, bo, x, BS, Dm, Dm);

  // 7) LN2
  ln_kernel<<<BS, 256, 0, stream>>>(hb, g2, s2, y2);

  // 8) FF1 + bias + GELU
  gemm_bt<1, true, false, true><<<dim3(64, 32), 256, 0, stream>>>(y2, w1T, ff1, b1, nullptr, BS, DFm, Dm);

  // 9) FF2 + bias + residual -> out (fp32)
  gemm_bt<0, true, true, false><<<dim3(64, 8), 256, 0, stream>>>(ff1, w2T, out, b2, hb, BS, Dm, DFm);
}

// Round 4
// 412.487 us; speedup vs baseline: 1.9328x; 1.0276x over previous
//
#include <hip/hip_runtime.h>
#include <hip/hip_bf16.h>

#define DEV __device__ __forceinline__

typedef __bf16 bf16x8 __attribute__((ext_vector_type(8)));
typedef __bf16 bf16x2v __attribute__((ext_vector_type(2)));
typedef float f32x4 __attribute__((ext_vector_type(4)));
typedef float f32x16 __attribute__((ext_vector_type(16)));
typedef unsigned int u32;
typedef unsigned int u32x4 __attribute__((ext_vector_type(4)));
typedef __hip_bfloat16 hbf;

constexpr int Dm = 1024;
constexpr int Hh = 16;
constexpr int Ss = 2048;
constexpr int Bb = 4;
constexpr int DFm = 4096;
constexpr int LDQ = 3072;  // fused qkv row stride

DEV unsigned short f2bfu(float f) {
  hbf h = __float2bfloat16(f);
  return __builtin_bit_cast(unsigned short, h);
}

DEV u32 pkbf(float x, float y) {
  bf16x2v v = {(__bf16)x, (__bf16)y};
  return __builtin_bit_cast(u32, v);
}

DEV float gelu_f(float x) {
  // 0.5x(1+tanh(z)) == x * sigmoid(2z), z = c*(x+0.044715x^3)
  return x / (1.f + __expf(-1.5957691216057308f * (x + 0.044715f * x * x * x)));
}

#define GLDS(src, dst)                                                                     \
  __builtin_amdgcn_global_load_lds((const __attribute__((address_space(1))) void*)(src),   \
                                   (__attribute__((address_space(3))) void*)(dst), 16, 0, 0)

// ---------------- weight transpose + fp32->bf16 convert: W[K,N] -> Wt[N,K] ----------------
__global__ __launch_bounds__(256) void wtrans_kernel(const float* __restrict__ W,
                                                     hbf* __restrict__ Wt, int K, int N) {
  __shared__ float tile[32][33];
  int k0 = blockIdx.x * 32, n0 = blockIdx.y * 32;
  int tx = threadIdx.x & 31, ty = threadIdx.x >> 5;
  for (int r = ty; r < 32; r += 8) tile[r][tx] = W[(size_t)(k0 + r) * N + n0 + tx];
  __syncthreads();
  for (int r = ty; r < 32; r += 8)
    Wt[(size_t)(n0 + r) * K + k0 + tx] = __float2bfloat16(tile[tx][r]);
}

// ---------------- layernorm (fp32 in, bf16 out), one block per row, D=1024 ----------------
__global__ __launch_bounds__(256) void ln_kernel(const float* __restrict__ x,
                                                 const float* __restrict__ g,
                                                 const float* __restrict__ b,
                                                 hbf* __restrict__ y) {
  int row = blockIdx.x;
  int t = threadIdx.x;
  const float4 v = ((const float4*)(x + (size_t)row * Dm))[t];
  float s = v.x + v.y + v.z + v.w;
  float q = v.x * v.x + v.y * v.y + v.z * v.z + v.w * v.w;
#pragma unroll
  for (int off = 32; off > 0; off >>= 1) {
    s += __shfl_down(s, off);
    q += __shfl_down(q, off);
  }
  __shared__ float red[10];
  int wave = t >> 6, lane = t & 63;
  if (lane == 0) { red[wave] = s; red[4 + wave] = q; }
  __syncthreads();
  if (t == 0) {
    float ts = red[0] + red[1] + red[2] + red[3];
    float tq = red[4] + red[5] + red[6] + red[7];
    float mean = ts * (1.f / Dm);
    float var = tq * (1.f / Dm) - mean * mean;
    red[8] = mean;
    red[9] = rsqrtf(var + 1e-5f);
  }
  __syncthreads();
  float mean = red[8], inv = red[9];
  float4 gv = ((const float4*)g)[t];
  float4 bv = ((const float4*)b)[t];
  ushort4 o;
  o.x = f2bfu(gv.x * (v.x - mean) * inv + bv.x);
  o.y = f2bfu(gv.y * (v.y - mean) * inv + bv.y);
  o.z = f2bfu(gv.z * (v.z - mean) * inv + bv.z);
  o.w = f2bfu(gv.w * (v.w - mean) * inv + bv.w);
  ((ushort4*)(y + (size_t)row * Dm))[t] = o;
}

// ================= 8-phase 256-tile GEMM (T2+T3+T4+T5) ====================================
// C[M,N] = A[M,K] @ Bt[N,K]^T, all bf16 in, fp32 acc. BM=256, BK=64, 8 waves (512 thr).
// LDS: 2 buffers x {A[ks0],A[ks1],B[ks0],B[ks1]} k-substep slabs. One slab staged per phase:
//   ph0: A(ks1,t+1)->buf^1 | ph1: B(ks0,t+2)->buf | ph2: A(ks0,t+2)->buf | ph3: B(ks1,t+2)->buf
// (each target slab provably dead: B(ks0) after ph0, A(ks0) after ph1, B(ks1) after ph2,
//  A(ks1) after ph3). Counted vmcnt(VC) once per K-tile at end of ph3 (VC=2*BLD+ALD);
// vmcnt(0) at the tail boundary where stages were skipped. Raw s_barrier only.
template <int BN, int WM, int WN, int ACT, bool HAS_BIAS, bool HAS_RES, bool OUT_BF16>
__global__ __launch_bounds__(512, 2) void gemm8(const hbf* __restrict__ A,
                                                const hbf* __restrict__ Bt,
                                                void* __restrict__ Cv,
                                                const float* __restrict__ bias,
                                                const float* __restrict__ res,
                                                int M, int N, int K) {
  constexpr int BM = 256;
  constexpr int ASZ = BM * 32;          // elements per A k-substep slab
  constexpr int BSZ = BN * 32;
  constexpr int BUF = 2 * (ASZ + BSZ);  // elements per double-buffer half
  constexpr int ALD = 2;                // global_load_lds per thread per A slab
  constexpr int BLD = BN / 128;
  constexpr int MR = (BM / WM) / 16, NR = (BN / WN) / 16, MH = MR / 2;
  constexpr int VC = 2 * BLD + ALD;     // counted vmcnt at K-tile boundary

  __shared__ __align__(16) hbf lds[2 * BUF];

  const int tid = threadIdx.x;
  const int lane = tid & 63, wave = tid >> 6;
  const int wr = wave / WN, wc = wave % WN;
  const int lr = lane & 15, lg = lane >> 4;

  // bijective XCD swizzle (m204)
  const int nwg = gridDim.x;
  const int qq = nwg >> 3, rr = nwg & 7;
  const int xcd = blockIdx.x & 7, oidx = blockIdx.x >> 3;
  const int wg = (xcd < rr ? xcd * (qq + 1) : rr * (qq + 1) + (xcd - rr) * qq) + oidx;
  const int ntn = N / BN;
  const int m0 = (wg / ntn) * BM, n0 = (wg % ntn) * BN;

  const hbf* Ab = A + (size_t)m0 * K;
  const hbf* Bb = Bt + (size_t)n0 * K;

  // read-side swizzle (involution with stage-source swizzle): 16B-chunk ^= (r&3)^((r>>2)&3)
  const int swz = ((lg ^ (lr & 3) ^ (lr >> 2)) & 3) * 8;

  f32x4 acc[MR][NR] = {};

  auto stageA = [&](int ks, int t, int p) {
#pragma unroll
    for (int l = 0; l < ALD; ++l) {
      int ci = l * 512 + tid;
      int r = ci >> 2, c = ci & 3;
      int cs = c ^ (r & 3) ^ ((r >> 2) & 3);
      GLDS(Ab + (size_t)r * K + t * 64 + ks * 32 + cs * 8,
           lds + p * BUF + ks * ASZ + ci * 8);
    }
  };
  auto stageB = [&](int ks, int t, int p) {
#pragma unroll
    for (int l = 0; l < BLD; ++l) {
      int ci = l * 512 + tid;
      int r = ci >> 2, c = ci & 3;
      int cs = c ^ (r & 3) ^ ((r >> 2) & 3);
      GLDS(Bb + (size_t)r * K + t * 64 + ks * 32 + cs * 8,
           lds + p * BUF + 2 * ASZ + ks * BSZ + ci * 8);
    }
  };
  auto loadA = [&](bf16x8* af, int mh, int ks, int p) {
#pragma unroll
    for (int i = 0; i < MH; ++i) {
      int row = wr * (BM / WM) + (mh * MH + i) * 16 + lr;
      af[i] = *(const bf16x8*)(lds + p * BUF + ks * ASZ + row * 32 + swz);
    }
  };
  auto loadB = [&](bf16x8* bfv, int ks, int p) {
#pragma unroll
    for (int n = 0; n < NR; ++n) {
      int row = wc * (BN / WN) + n * 16 + lr;
      bfv[n] = *(const bf16x8*)(lds + p * BUF + 2 * ASZ + ks * BSZ + row * 32 + swz);
    }
  };

#define PHASE_SYNC()                                       \
  do {                                                     \
    __builtin_amdgcn_s_barrier();                          \
    asm volatile("s_waitcnt lgkmcnt(0)" ::: "memory");     \
    __builtin_amdgcn_sched_barrier(0);                     \
  } while (0)

#define DO_MFMA(afv, bfv, mh)                                                         \
  do {                                                                                \
    __builtin_amdgcn_s_setprio(1);                                                    \
    _Pragma("unroll") for (int i_ = 0; i_ < MH; ++i_)                                 \
        _Pragma("unroll") for (int n_ = 0; n_ < NR; ++n_)                             \
            acc[(mh) * MH + i_][n_] = __builtin_amdgcn_mfma_f32_16x16x32_bf16(        \
                (afv)[i_], (bfv)[n_], acc[(mh) * MH + i_][n_], 0, 0, 0);              \
    __builtin_amdgcn_s_setprio(0);                                                    \
  } while (0)

  // prologue: tile0 fully + tile1 minus A(ks1)
  stageB(0, 0, 0); stageA(0, 0, 0); stageB(1, 0, 0); stageA(1, 0, 0);
  stageB(0, 1, 1); stageA(0, 1, 1); stageB(1, 1, 1);
  if constexpr (VC == 6) asm volatile("s_waitcnt vmcnt(6)" ::: "memory");
  else asm volatile("s_waitcnt vmcnt(4)" ::: "memory");
  __builtin_amdgcn_s_barrier();

  const int T = K >> 6;
  for (int t = 0; t < T; ++t) {
    const int p = t & 1;
    bf16x8 af0[MH], af1[MH], bfr[NR];
    // ---- ph0: (ks0, mh0) ----
    loadA(af0, 0, 0, p);
    loadB(bfr, 0, p);
    if (t + 1 < T) stageA(1, t + 1, p ^ 1);
    PHASE_SYNC();
    DO_MFMA(af0, bfr, 0);
    __builtin_amdgcn_s_barrier();
    // ---- ph1: (ks0, mh1) ----
    loadA(af1, 1, 0, p);
    if (t + 2 < T) stageB(0, t + 2, p);
    PHASE_SYNC();
    DO_MFMA(af1, bfr, 1);
    __builtin_amdgcn_s_barrier();
    // ---- ph2: (ks1, mh0) ----
    loadA(af0, 0, 1, p);
    loadB(bfr, 1, p);
    if (t + 2 < T) stageA(0, t + 2, p);
    PHASE_SYNC();
    DO_MFMA(af0, bfr, 0);
    __builtin_amdgcn_s_barrier();
    // ---- ph3: (ks1, mh1) ----
    loadA(af1, 1, 1, p);
    if (t + 2 < T) stageB(1, t + 2, p);
    PHASE_SYNC();
    DO_MFMA(af1, bfr, 1);
    if (t + 1 < T) {
      if (t + 2 < T) {
        if constexpr (VC == 6) asm volatile("s_waitcnt vmcnt(6)" ::: "memory");
        else asm volatile("s_waitcnt vmcnt(4)" ::: "memory");
      } else {
        asm volatile("s_waitcnt vmcnt(0)" ::: "memory");
      }
    }
    __builtin_amdgcn_s_barrier();
  }
#undef PHASE_SYNC
#undef DO_MFMA

  // ---- epilogue ----
#pragma unroll
  for (int mf = 0; mf < MR; ++mf) {
    int row = m0 + wr * (BM / WM) + mf * 16 + lg * 4;
#pragma unroll
    for (int n = 0; n < NR; ++n) {
      int col = n0 + wc * (BN / WN) + n * 16 + lr;
      float bvl = HAS_BIAS ? bias[col] : 0.f;
#pragma unroll
      for (int j = 0; j < 4; ++j) {
        float v = acc[mf][n][j] + bvl;
        if (ACT == 1) v = gelu_f(v);
        if (HAS_RES) v += res[(size_t)(row + j) * N + col];
        if (OUT_BF16) ((hbf*)Cv)[(size_t)(row + j) * N + col] = __float2bfloat16(v);
        else ((float*)Cv)[(size_t)(row + j) * N + col] = v;
      }
    }
  }
}

// ---------------- per-head V transpose: qkv[b,s,2048+h*64+d] -> vt[(b*H+h)*64+d, s] -------
__global__ __launch_bounds__(256) void vtrans_kernel(const hbf* __restrict__ qkv,
                                                     hbf* __restrict__ vt) {
  __shared__ unsigned short tile[64][65];
  int bh = blockIdx.y, b = bh >> 4, hh = bh & 15;
  int s0 = blockIdx.x * 64;
  int d = threadIdx.x & 63, r0 = threadIdx.x >> 6;
#pragma unroll
  for (int i = 0; i < 16; ++i) {
    int r = r0 * 16 + i;
    tile[d][r] = __builtin_bit_cast(unsigned short,
                                    qkv[(size_t)(b * Ss + s0 + r) * LDQ + 2048 + hh * 64 + d]);
  }
  __syncthreads();
#pragma unroll
  for (int i = 0; i < 16; ++i) {
    int r = r0 * 16 + i;
    vt[(size_t)(bh * 64 + r) * Ss + s0 + d] = __builtin_bit_cast(hbf, tile[r][d]);
  }
}

// ---------------- causal flash attention, swapped QK^T, in-register softmax ---------------
__global__ __launch_bounds__(256, 3) void attn_kernel(const hbf* __restrict__ qkv,
                                                      const hbf* __restrict__ vt,
                                                      hbf* __restrict__ ctx) {
  __shared__ __align__(16) hbf Ks[2][64 * 64];
  __shared__ __align__(16) hbf Vs[2][64 * 64];

  const int tid = threadIdx.x;
  const int wave = tid >> 6, lane = tid & 63;
  const int l31 = lane & 31, hi = lane >> 5;

  const int gi = blockIdx.x;
  const int g = gi >> 9, rr_ = gi & 511;
  const int bh = rr_ >> 3, j = rr_ & 7;
  const int bx = g ? j : 15 - j;
  const int b = bh >> 4, hh = bh & 15;
  const int q0b = bx * 128;
  const int q0w = q0b + wave * 32;
  const int nsteps = (q0b + 128) >> 6;
  const int my_steps = (q0w + 95) >> 6;

  constexpr float QSCALE = 0.18033688011112042f;  // 0.125 * log2(e)
  bf16x8 qf[4];
  {
    const hbf* qrow = qkv + (size_t)(b * Ss + q0w + l31) * LDQ + hh * 64 + hi * 8;
#pragma unroll
    for (int ds = 0; ds < 4; ++ds) {
      bf16x8 t = *(const bf16x8*)(qrow + ds * 16);
#pragma unroll
      for (int e = 0; e < 8; ++e) qf[ds][e] = (__bf16)((float)t[e] * QSCALE);
    }
  }

  const hbf* kbase = qkv + 1024 + (size_t)(b * Ss) * LDQ + hh * 64;
  const hbf* vbase = vt + (size_t)(bh * 64) * Ss;
  const int i0 = tid, i1 = tid + 256;
  const int r0 = i0 >> 3, s0c = (i0 & 7), r1 = i1 >> 3, s1c = (i1 & 7);
  const int c0 = 8 * (s0c ^ (r0 & 7)), c1 = 8 * (s1c ^ (r1 & 7));

  f32x16 ot[2] = {};
  float m_run = -1e30f, l_run = 0.f;

  {
    hbf* kd = &Ks[0][0];
    hbf* vd = &Vs[0][0];
    GLDS(kbase + (size_t)r0 * LDQ + c0, kd + i0 * 8);
    GLDS(kbase + (size_t)r1 * LDQ + c1, kd + i1 * 8);
    GLDS(vbase + (size_t)r0 * Ss + c0, vd + i0 * 8);
    GLDS(vbase + (size_t)r1 * Ss + c1, vd + i1 * 8);
  }
  __syncthreads();

  int buf = 0;
  for (int it = 0; it < nsteps; ++it) {
    const int k0 = it << 6;
    if (it + 1 < nsteps) {
      hbf* kd = &Ks[buf ^ 1][0];
      hbf* vd = &Vs[buf ^ 1][0];
      GLDS(kbase + (size_t)(k0 + 64 + r0) * LDQ + c0, kd + i0 * 8);
      GLDS(kbase + (size_t)(k0 + 64 + r1) * LDQ + c1, kd + i1 * 8);
      GLDS(vbase + (size_t)r0 * Ss + k0 + 64 + c0, vd + i0 * 8);
      GLDS(vbase + (size_t)r1 * Ss + k0 + 64 + c1, vd + i1 * 8);
    }

    if (it < my_steps) {
      const hbf* kt = &Ks[buf][0];
      f32x16 st[2] = {};
#pragma unroll
      for (int c = 0; c < 2; ++c) {
        const int krow = l31 + 32 * c;
        const int kr7 = krow & 7;
#pragma unroll
        for (int ds = 0; ds < 4; ++ds) {
          bf16x8 kf = *(const bf16x8*)(kt + krow * 64 + 8 * ((ds * 2 + hi) ^ kr7));
          st[c] = __builtin_amdgcn_mfma_f32_32x32x16_bf16(kf, qf[ds], st[c], 0, 0, 0);
        }
      }

      if (it == my_steps - 1) {
        const int qg = q0w + l31;
#pragma unroll
        for (int c = 0; c < 2; ++c)
#pragma unroll
          for (int rg = 0; rg < 16; ++rg) {
            int kg = k0 + c * 32 + (rg & 3) + 8 * (rg >> 2) + 4 * hi;
            if (kg > qg) st[c][rg] = -3e38f;
          }
      }

      float mx = -3e38f;
#pragma unroll
      for (int c = 0; c < 2; ++c)
#pragma unroll
        for (int rg = 0; rg < 16; ++rg) mx = fmaxf(mx, st[c][rg]);
      mx = fmaxf(mx, __shfl_xor(mx, 32));
      if (!__all(mx - m_run <= 11.541560327111707f)) {
        float mn = fmaxf(m_run, mx);
        float sc = exp2f(m_run - mn);
        m_run = mn;
        l_run *= sc;
#pragma unroll
        for (int dc = 0; dc < 2; ++dc)
#pragma unroll
          for (int rg = 0; rg < 16; ++rg) ot[dc][rg] *= sc;
      }
      float rs = 0.f;
#pragma unroll
      for (int c = 0; c < 2; ++c)
#pragma unroll
        for (int rg = 0; rg < 16; ++rg) {
          float p = exp2f(st[c][rg] - m_run);
          st[c][rg] = p;
          rs += p;
        }
      rs += __shfl_xor(rs, 32);
      l_run += rs;

      bf16x8 pf[2][2];
#pragma unroll
      for (int c = 0; c < 2; ++c)
#pragma unroll
        for (int ks = 0; ks < 2; ++ks) {
          const int rb = ks * 8;
          u32 a0 = pkbf(st[c][rb + 0], st[c][rb + 1]);
          u32 a1 = pkbf(st[c][rb + 2], st[c][rb + 3]);
          u32 b0 = pkbf(st[c][rb + 4], st[c][rb + 5]);
          u32 b1 = pkbf(st[c][rb + 6], st[c][rb + 7]);
          u32 pa0 = __shfl_xor(a0, 32), pa1 = __shfl_xor(a1, 32);
          u32 pb0 = __shfl_xor(b0, 32), pb1 = __shfl_xor(b1, 32);
          u32x4 f;
          f.x = hi ? pb0 : a0;
          f.y = hi ? pb1 : a1;
          f.z = hi ? b0 : pa0;
          f.w = hi ? b1 : pa1;
          pf[c][ks] = __builtin_bit_cast(bf16x8, f);
        }

      const hbf* vtl = &Vs[buf][0];
#pragma unroll
      for (int dc = 0; dc < 2; ++dc) {
        const int vrow = l31 + 32 * dc;
        const int vr7 = vrow & 7;
#pragma unroll
        for (int c = 0; c < 2; ++c)
#pragma unroll
          for (int ks = 0; ks < 2; ++ks) {
            bf16x8 vf = *(const bf16x8*)(vtl + vrow * 64 + 8 * ((c * 4 + ks * 2 + hi) ^ vr7));
            ot[dc] = __builtin_amdgcn_mfma_f32_32x32x16_bf16(vf, pf[c][ks], ot[dc], 0, 0, 0);
          }
      }
    }

    __syncthreads();
    buf ^= 1;
  }

  const float inv = 1.f / l_run;
  hbf* crow = ctx + (size_t)(b * Ss + q0w + l31) * Dm + hh * 64;
#pragma unroll
  for (int dc = 0; dc < 2; ++dc)
#pragma unroll
    for (int rg = 0; rg < 4; ++rg) {
      ushort4 w;
      w.x = f2bfu(ot[dc][rg * 4 + 0] * inv);
      w.y = f2bfu(ot[dc][rg * 4 + 1] * inv);
      w.z = f2bfu(ot[dc][rg * 4 + 2] * inv);
      w.w = f2bfu(ot[dc][rg * 4 + 3] * inv);
      *(ushort4*)(crow + dc * 32 + rg * 8 + hi * 4) = w;
    }
}

// -----------------------------------------------------------------------------------------
extern "C" void kernel_launch(void* const* d_in, const int* in_sizes, int n_in,
                              void* d_out, int out_size, void* d_ws, size_t ws_size,
                              hipStream_t stream) {
  const float* x  = (const float*)d_in[0];
  const float* Wq = (const float*)d_in[1];
  const float* Wk = (const float*)d_in[2];
  const float* Wv = (const float*)d_in[3];
  const float* Wo = (const float*)d_in[4];
  const float* bo = (const float*)d_in[5];
  const float* W1 = (const float*)d_in[6];
  const float* b1 = (const float*)d_in[7];
  const float* W2 = (const float*)d_in[8];
  const float* b2 = (const float*)d_in[9];
  const float* g1 = (const float*)d_in[10];
  const float* s1 = (const float*)d_in[11];
  const float* g2 = (const float*)d_in[12];
  const float* s2 = (const float*)d_in[13];
  float* out = (float*)d_out;

  char* ws = (char*)d_ws;
  constexpr size_t MB = 1024ull * 1024ull;
  hbf* wqkvT = (hbf*)(ws + 0 * MB);    // 6MB [3072][1024]
  hbf* woT   = (hbf*)(ws + 6 * MB);    // 2MB
  hbf* w1T   = (hbf*)(ws + 8 * MB);    // 8MB
  hbf* w2T   = (hbf*)(ws + 16 * MB);   // 8MB
  hbf* xln   = (hbf*)(ws + 24 * MB);   // 16MB (reused: ctx, then y2)
  hbf* ctx   = (hbf*)(ws + 24 * MB);
  hbf* y2    = (hbf*)(ws + 24 * MB);
  hbf* qkvb  = (hbf*)(ws + 40 * MB);   // 48MB [8192][3072]
  hbf* vtb   = (hbf*)(ws + 88 * MB);   // 16MB
  hbf* ff1   = (hbf*)(ws + 40 * MB);   // 64MB (over dead qkv/vt)
  float* hb  = (float*)(ws + 104 * MB); // 32MB fp32
  (void)ws_size; (void)in_sizes; (void)n_in; (void)out_size;

  const int BS = Bb * Ss;  // 8192 rows

  // 1) weights -> bf16 transposed [N,K]; QKV packed into one [3072][1024]
  wtrans_kernel<<<dim3(32, 32), 256, 0, stream>>>(Wq, wqkvT, Dm, Dm);
  wtrans_kernel<<<dim3(32, 32), 256, 0, stream>>>(Wk, wqkvT + 1024 * 1024, Dm, Dm);
  wtrans_kernel<<<dim3(32, 32), 256, 0, stream>>>(Wv, wqkvT + 2 * 1024 * 1024, Dm, Dm);
  wtrans_kernel<<<dim3(32, 32), 256, 0, stream>>>(Wo, woT, Dm, Dm);
  wtrans_kernel<<<dim3(32, 128), 256, 0, stream>>>(W1, w1T, Dm, DFm);
  wtrans_kernel<<<dim3(128, 32), 256, 0, stream>>>(W2, w2T, DFm, Dm);

  // 2) LN1
  ln_kernel<<<BS, 256, 0, stream>>>(x, g1, s1, xln);

  // 3) fused QKV projection: [8192,1024] @ [1024,3072]  (grid 32*12=384)
  gemm8<256, 2, 4, 0, false, false, true><<<384, 512, 0, stream>>>(xln, wqkvT, qkvb, nullptr, nullptr, BS, LDQ, Dm);

  // 4) V transpose per head
  vtrans_kernel<<<dim3(Ss / 64, Bb * Hh), 256, 0, stream>>>(qkvb, vtb);

  // 5) flash attention
  attn_kernel<<<dim3(1024), 256, 0, stream>>>(qkvb, vtb, ctx);

  // 6) output projection + bias + residual -> h (fp32)  (grid 32*8=256, BN=128)
  gemm8<128, 4, 2, 0, true, true, false><<<256, 512, 0, stream>>>(ctx, woT, hb, bo, x, BS, Dm, Dm);

  // 7) LN2
  ln_kernel<<<BS, 256, 0, stream>>>(hb, g2, s2, y2);

  // 8) FF1 + bias + GELU  (grid 32*16=512)
  gemm8<256, 2, 4, 1, true, false, true><<<512, 512, 0, stream>>>(y2, w1T, ff1, b1, nullptr, BS, DFm, Dm);

  // 9) FF2 + bias + residual -> out (fp32)  (grid 32*8=256, BN=128, K=4096)
  gemm8<128, 4, 2, 0, true, true, false><<<256, 512, 0, stream>>>(ff1, w2T, out, b2, hb, BS, Dm, DFm);
}

// Round 5
// 387.318 us; speedup vs baseline: 2.0585x; 1.0650x over previous
//
#include <hip/hip_runtime.h>
#include <hip/hip_bf16.h>

#define DEV __device__ __forceinline__

typedef __bf16 bf16x8 __attribute__((ext_vector_type(8)));
typedef __bf16 bf16x2v __attribute__((ext_vector_type(2)));
typedef float f32x4 __attribute__((ext_vector_type(4)));
typedef float f32x16 __attribute__((ext_vector_type(16)));
typedef unsigned int u32;
typedef unsigned int u32x4 __attribute__((ext_vector_type(4)));
typedef __hip_bfloat16 hbf;

constexpr int Dm = 1024;
constexpr int Hh = 16;
constexpr int Ss = 2048;
constexpr int Bb = 4;
constexpr int DFm = 4096;
constexpr int LDQ = 3072;  // fused qkv row stride

DEV unsigned short f2bfu(float f) {
  hbf h = __float2bfloat16(f);
  return __builtin_bit_cast(unsigned short, h);
}

DEV u32 pkbf(float x, float y) {
  bf16x2v v = {(__bf16)x, (__bf16)y};
  return __builtin_bit_cast(u32, v);
}

DEV float gelu_f(float x) {
  // 0.5x(1+tanh(z)) == x * sigmoid(2z), z = c*(x+0.044715x^3)
  return x / (1.f + __expf(-1.5957691216057308f * (x + 0.044715f * x * x * x)));
}

#define GLDS(src, dst)                                                                     \
  __builtin_amdgcn_global_load_lds((const __attribute__((address_space(1))) void*)(src),   \
                                   (__attribute__((address_space(3))) void*)(dst), 16, 0, 0)

// ---------------- weight transpose + fp32->bf16 convert: W[K,N] -> Wt[N,K] ----------------
__global__ __launch_bounds__(256) void wtrans_kernel(const float* __restrict__ W,
                                                     hbf* __restrict__ Wt, int K, int N) {
  __shared__ float tile[32][33];
  int k0 = blockIdx.x * 32, n0 = blockIdx.y * 32;
  int tx = threadIdx.x & 31, ty = threadIdx.x >> 5;
  for (int r = ty; r < 32; r += 8) tile[r][tx] = W[(size_t)(k0 + r) * N + n0 + tx];
  __syncthreads();
  for (int r = ty; r < 32; r += 8)
    Wt[(size_t)(n0 + r) * K + k0 + tx] = __float2bfloat16(tile[tx][r]);
}

// 4 square 1024x1024 weights in one launch (z picks weight)
__global__ __launch_bounds__(256) void wtrans4_kernel(const float* __restrict__ W0,
                                                      const float* __restrict__ W1,
                                                      const float* __restrict__ W2,
                                                      const float* __restrict__ W3,
                                                      hbf* __restrict__ D0, hbf* __restrict__ D1,
                                                      hbf* __restrict__ D2, hbf* __restrict__ D3) {
  __shared__ float tile[32][33];
  const int z = blockIdx.z;
  const float* W = z == 0 ? W0 : z == 1 ? W1 : z == 2 ? W2 : W3;
  hbf* Wt = z == 0 ? D0 : z == 1 ? D1 : z == 2 ? D2 : D3;
  int k0 = blockIdx.x * 32, n0 = blockIdx.y * 32;
  int tx = threadIdx.x & 31, ty = threadIdx.x >> 5;
  for (int r = ty; r < 32; r += 8) tile[r][tx] = W[(size_t)(k0 + r) * 1024 + n0 + tx];
  __syncthreads();
  for (int r = ty; r < 32; r += 8)
    Wt[(size_t)(n0 + r) * 1024 + k0 + tx] = __float2bfloat16(tile[tx][r]);
}

// ---------------- layernorm (fp32 in, bf16 out), one block per row, D=1024 ----------------
__global__ __launch_bounds__(256) void ln_kernel(const float* __restrict__ x,
                                                 const float* __restrict__ g,
                                                 const float* __restrict__ b,
                                                 hbf* __restrict__ y) {
  int row = blockIdx.x;
  int t = threadIdx.x;
  const float4 v = ((const float4*)(x + (size_t)row * Dm))[t];
  float s = v.x + v.y + v.z + v.w;
  float q = v.x * v.x + v.y * v.y + v.z * v.z + v.w * v.w;
#pragma unroll
  for (int off = 32; off > 0; off >>= 1) {
    s += __shfl_down(s, off);
    q += __shfl_down(q, off);
  }
  __shared__ float red[10];
  int wave = t >> 6, lane = t & 63;
  if (lane == 0) { red[wave] = s; red[4 + wave] = q; }
  __syncthreads();
  if (t == 0) {
    float ts = red[0] + red[1] + red[2] + red[3];
    float tq = red[4] + red[5] + red[6] + red[7];
    float mean = ts * (1.f / Dm);
    float var = tq * (1.f / Dm) - mean * mean;
    red[8] = mean;
    red[9] = rsqrtf(var + 1e-5f);
  }
  __syncthreads();
  float mean = red[8], inv = red[9];
  float4 gv = ((const float4*)g)[t];
  float4 bv = ((const float4*)b)[t];
  ushort4 o;
  o.x = f2bfu(gv.x * (v.x - mean) * inv + bv.x);
  o.y = f2bfu(gv.y * (v.y - mean) * inv + bv.y);
  o.z = f2bfu(gv.z * (v.z - mean) * inv + bv.z);
  o.w = f2bfu(gv.w * (v.w - mean) * inv + bv.w);
  ((ushort4*)(y + (size_t)row * Dm))[t] = o;
}

// ================= 8-phase 256-tile GEMM, m201 slab geometry ==============================
// C[M,N] = A[M,K](bf16) @ Bt[N,K]^T(bf16). BM=256, BK=64, 512 thr = 8 waves (WM x WN).
// LDS slabs per buffer: A-half(mh) = union over wr of rows [wr*(BM/WM)+mh*RPA, +RPA) x BK
// (128 rows x 128B contiguous), B-half(nh) likewise (BN/2 rows). Phases = C-quadrants in
// order (0,0),(1,0),(1,1),(0,1); A/B fragment regs persist 2+ phases. ds_reads per phase:
// {12,8,4,0}. Stages: P1:A0(t+2), P2:B0+A1(t+2), P3:B1(t+2) -> current buf (each slab dead
// by then; verified vs 2-buffer reuse). Boundary s_waitcnt vmcnt(LPI) keeps t+2's LPI loads
// in flight, drains t+1's. Raw s_barrier only; lgkmcnt(0)+sched_barrier before each MFMA.
template <int BN, int WM, int WN, int ACT, bool HAS_BIAS, bool HAS_RES, bool OUT_BF16>
__global__ __launch_bounds__(512, 2) void gemm8(const hbf* __restrict__ A,
                                                const hbf* __restrict__ Bt,
                                                void* __restrict__ Cv,
                                                const float* __restrict__ bias,
                                                const float* __restrict__ res,
                                                int M, int N, int K) {
  constexpr int BM = 256;
  constexpr int MR = (BM / WM) / 16, NR = (BN / WN) / 16;
  constexpr int MQ = MR / 2, NQ = NR / 2;
  constexpr int RPA = (BM / WM) / 2;        // rows per A piece (per wr)
  constexpr int RPB = (BN / WN) / 2;        // rows per B piece (per wc)
  constexpr int ASL = 128 * 64;             // A-half slab elems (128 rows x 64)
  constexpr int BSL = (BN / 2) * 64;        // B-half slab elems
  constexpr int PERBUF = 2 * ASL + 2 * BSL;
  constexpr int ALD = 2;                    // gload_lds per thread per A slab
  constexpr int BLD = BN / 128;             // per B slab
  constexpr int LPI = 2 * ALD + 2 * BLD;    // loads per iter = vmcnt keep-count

  __shared__ __align__(16) hbf lds[2 * PERBUF];

  const int tid = threadIdx.x;
  const int lane = tid & 63, wave = tid >> 6;
  const int wr = wave / WN, wc = wave % WN;
  const int lr = lane & 15, lg = lane >> 4;

  // bijective XCD swizzle (m204)
  const int nwg = gridDim.x;
  const int qq = nwg >> 3, rr = nwg & 7;
  const int xcd = blockIdx.x & 7, oidx = blockIdx.x >> 3;
  const int wg = (xcd < rr ? xcd * (qq + 1) : rr * (qq + 1) + (xcd - rr) * qq) + oidx;
  const int ntn = N / BN;
  const int m0 = (wg / ntn) * BM, n0 = (wg % ntn) * BN;

  const hbf* Ab = A + (size_t)m0 * K;
  const hbf* Bb = Bt + (size_t)n0 * K;

  f32x4 acc[MR][NR] = {};

  // ---- staging: swizzled source chunk c^(r&7), linear LDS dest ----
  auto stageA = [&](int mh, int t, int p) {
#pragma unroll
    for (int l = 0; l < ALD; ++l) {
      int ci = l * 512 + tid;
      int r = ci >> 3, c = ci & 7;
      int piece = r / RPA, rl = r % RPA;
      int grow = piece * (BM / WM) + mh * RPA + rl;
      int gk = t * 64 + ((c ^ (r & 7)) << 3);
      GLDS(Ab + (size_t)grow * K + gk, lds + p * PERBUF + mh * ASL + (size_t)ci * 8);
    }
  };
  auto stageB = [&](int nh, int t, int p) {
#pragma unroll
    for (int l = 0; l < BLD; ++l) {
      int ci = l * 512 + tid;
      int r = ci >> 3, c = ci & 7;
      int piece = r / RPB, rl = r % RPB;
      int grow = piece * (BN / WN) + nh * RPB + rl;
      int gk = t * 64 + ((c ^ (r & 7)) << 3);
      GLDS(Bb + (size_t)grow * K + gk, lds + p * PERBUF + 2 * ASL + nh * BSL + (size_t)ci * 8);
    }
  };
  // ---- fragment reads: slot (ks*4+lg)^(lr&7) ----
  auto ldA = [&](bf16x8 (&af)[MQ][2], int mh, int p) {
    const hbf* base = lds + p * PERBUF + mh * ASL;
#pragma unroll
    for (int i = 0; i < MQ; ++i)
#pragma unroll
      for (int ks = 0; ks < 2; ++ks) {
        int row = wr * RPA + i * 16 + lr;
        int slot = (ks * 4 + lg) ^ (lr & 7);
        af[i][ks] = *(const bf16x8*)(base + (size_t)row * 64 + slot * 8);
      }
  };
  auto ldB = [&](bf16x8 (&bf)[NQ][2], int nh, int p) {
    const hbf* base = lds + p * PERBUF + 2 * ASL + nh * BSL;
#pragma unroll
    for (int j = 0; j < NQ; ++j)
#pragma unroll
      for (int ks = 0; ks < 2; ++ks) {
        int row = wc * RPB + j * 16 + lr;
        int slot = (ks * 4 + lg) ^ (lr & 7);
        bf[j][ks] = *(const bf16x8*)(base + (size_t)row * 64 + slot * 8);
      }
  };

#define SYNC_LGKM()                                        \
  do {                                                     \
    __builtin_amdgcn_s_barrier();                          \
    asm volatile("s_waitcnt lgkmcnt(0)" ::: "memory");     \
    __builtin_amdgcn_sched_barrier(0);                     \
  } while (0)

#define MFMA_Q(av, bv, mh, nh)                                                        \
  do {                                                                                \
    __builtin_amdgcn_s_setprio(1);                                                    \
    _Pragma("unroll") for (int i_ = 0; i_ < MQ; ++i_)                                 \
    _Pragma("unroll") for (int j_ = 0; j_ < NQ; ++j_)                                 \
    _Pragma("unroll") for (int k_ = 0; k_ < 2; ++k_)                                  \
      acc[(mh) * MQ + i_][(nh) * NQ + j_] = __builtin_amdgcn_mfma_f32_16x16x32_bf16(  \
          (av)[i_][k_], (bv)[j_][k_], acc[(mh) * MQ + i_][(nh) * NQ + j_], 0, 0, 0);  \
    __builtin_amdgcn_s_setprio(0);                                                    \
  } while (0)

  // prologue: tiles 0 and 1 fully staged
  stageA(0, 0, 0); stageB(0, 0, 0); stageA(1, 0, 0); stageB(1, 0, 0);
  stageA(0, 1, 1); stageB(0, 1, 1); stageA(1, 1, 1); stageB(1, 1, 1);
  if constexpr (LPI == 8) asm volatile("s_waitcnt vmcnt(8)" ::: "memory");
  else asm volatile("s_waitcnt vmcnt(6)" ::: "memory");
  __builtin_amdgcn_s_barrier();

  const int T = K >> 6;
  for (int t = 0; t < T; ++t) {
    const int p = t & 1;
    bf16x8 a0[MQ][2], a1[MQ][2], b0[NQ][2], b1[NQ][2];
    // ---- P0: quadrant (0,0); no stage; 12 (or 8) ds_reads ----
    ldA(a0, 0, p);
    ldB(b0, 0, p);
    if constexpr (MQ * 2 + NQ * 2 == 12) asm volatile("s_waitcnt lgkmcnt(8)" ::: "memory");
    SYNC_LGKM();
    MFMA_Q(a0, b0, 0, 0);
    __builtin_amdgcn_s_barrier();
    // ---- P1: quadrant (1,0); stage A0(t+2) ----
    ldA(a1, 1, p);
    if (t + 2 < T) stageA(0, t + 2, p);
    SYNC_LGKM();
    MFMA_Q(a1, b0, 1, 0);
    __builtin_amdgcn_s_barrier();
    // ---- P2: quadrant (1,1); stage B0(t+2), A1(t+2) ----
    ldB(b1, 1, p);
    if (t + 2 < T) { stageB(0, t + 2, p); stageA(1, t + 2, p); }
    SYNC_LGKM();
    MFMA_Q(a1, b1, 1, 1);
    __builtin_amdgcn_s_barrier();
    // ---- P3: quadrant (0,1); no ds_reads; stage B1(t+2); boundary vmcnt ----
    if (t + 2 < T) stageB(1, t + 2, p);
    MFMA_Q(a0, b1, 0, 1);
    if (t + 1 < T) {
      if (t + 2 < T) {
        if constexpr (LPI == 8) asm volatile("s_waitcnt vmcnt(8)" ::: "memory");
        else asm volatile("s_waitcnt vmcnt(6)" ::: "memory");
      } else {
        asm volatile("s_waitcnt vmcnt(0)" ::: "memory");
      }
    }
    __builtin_amdgcn_s_barrier();
  }
#undef SYNC_LGKM
#undef MFMA_Q

  // ---- epilogue ----
#pragma unroll
  for (int mf = 0; mf < MR; ++mf) {
    int row = m0 + wr * (BM / WM) + mf * 16 + lg * 4;
#pragma unroll
    for (int n = 0; n < NR; ++n) {
      int col = n0 + wc * (BN / WN) + n * 16 + lr;
      float bvl = HAS_BIAS ? bias[col] : 0.f;
#pragma unroll
      for (int j = 0; j < 4; ++j) {
        float v = acc[mf][n][j] + bvl;
        if (ACT == 1) v = gelu_f(v);
        if (HAS_RES) v += res[(size_t)(row + j) * N + col];
        if (OUT_BF16) ((hbf*)Cv)[(size_t)(row + j) * N + col] = __float2bfloat16(v);
        else ((float*)Cv)[(size_t)(row + j) * N + col] = v;
      }
    }
  }
}

// ---------------- per-head V transpose: qkv[b,s,2048+h*64+d] -> vt[(b*H+h)*64+d, s] -------
__global__ __launch_bounds__(256) void vtrans_kernel(const hbf* __restrict__ qkv,
                                                     hbf* __restrict__ vt) {
  __shared__ unsigned short tile[64][65];
  int bh = blockIdx.y, b = bh >> 4, hh = bh & 15;
  int s0 = blockIdx.x * 64;
  int d = threadIdx.x & 63, r0 = threadIdx.x >> 6;
#pragma unroll
  for (int i = 0; i < 16; ++i) {
    int r = r0 * 16 + i;
    tile[d][r] = __builtin_bit_cast(unsigned short,
                                    qkv[(size_t)(b * Ss + s0 + r) * LDQ + 2048 + hh * 64 + d]);
  }
  __syncthreads();
#pragma unroll
  for (int i = 0; i < 16; ++i) {
    int r = r0 * 16 + i;
    vt[(size_t)(bh * 64 + r) * Ss + s0 + d] = __builtin_bit_cast(hbf, tile[r][d]);
  }
}

// ---------------- causal flash attention, swapped QK^T, in-register softmax ---------------
__global__ __launch_bounds__(256, 3) void attn_kernel(const hbf* __restrict__ qkv,
                                                      const hbf* __restrict__ vt,
                                                      hbf* __restrict__ ctx) {
  __shared__ __align__(16) hbf Ks[2][64 * 64];
  __shared__ __align__(16) hbf Vs[2][64 * 64];

  const int tid = threadIdx.x;
  const int wave = tid >> 6, lane = tid & 63;
  const int l31 = lane & 31, hi = lane >> 5;

  const int gi = blockIdx.x;
  const int g = gi >> 9, rr_ = gi & 511;
  const int bh = rr_ >> 3, j = rr_ & 7;
  const int bx = g ? j : 15 - j;
  const int b = bh >> 4, hh = bh & 15;
  const int q0b = bx * 128;
  const int q0w = q0b + wave * 32;
  const int nsteps = (q0b + 128) >> 6;
  const int my_steps = (q0w + 95) >> 6;

  constexpr float QSCALE = 0.18033688011112042f;  // 0.125 * log2(e)
  bf16x8 qf[4];
  {
    const hbf* qrow = qkv + (size_t)(b * Ss + q0w + l31) * LDQ + hh * 64 + hi * 8;
#pragma unroll
    for (int ds = 0; ds < 4; ++ds) {
      bf16x8 t = *(const bf16x8*)(qrow + ds * 16);
#pragma unroll
      for (int e = 0; e < 8; ++e) qf[ds][e] = (__bf16)((float)t[e] * QSCALE);
    }
  }

  const hbf* kbase = qkv + 1024 + (size_t)(b * Ss) * LDQ + hh * 64;
  const hbf* vbase = vt + (size_t)(bh * 64) * Ss;
  const int i0 = tid, i1 = tid + 256;
  const int r0 = i0 >> 3, s0c = (i0 & 7), r1 = i1 >> 3, s1c = (i1 & 7);
  const int c0 = 8 * (s0c ^ (r0 & 7)), c1 = 8 * (s1c ^ (r1 & 7));

  f32x16 ot[2] = {};
  float m_run = -1e30f, l_run = 0.f;

  {
    hbf* kd = &Ks[0][0];
    hbf* vd = &Vs[0][0];
    GLDS(kbase + (size_t)r0 * LDQ + c0, kd + i0 * 8);
    GLDS(kbase + (size_t)r1 * LDQ + c1, kd + i1 * 8);
    GLDS(vbase + (size_t)r0 * Ss + c0, vd + i0 * 8);
    GLDS(vbase + (size_t)r1 * Ss + c1, vd + i1 * 8);
  }
  __syncthreads();

  int buf = 0;
  for (int it = 0; it < nsteps; ++it) {
    const int k0 = it << 6;
    if (it + 1 < nsteps) {
      hbf* kd = &Ks[buf ^ 1][0];
      hbf* vd = &Vs[buf ^ 1][0];
      GLDS(kbase + (size_t)(k0 + 64 + r0) * LDQ + c0, kd + i0 * 8);
      GLDS(kbase + (size_t)(k0 + 64 + r1) * LDQ + c1, kd + i1 * 8);
      GLDS(vbase + (size_t)r0 * Ss + k0 + 64 + c0, vd + i0 * 8);
      GLDS(vbase + (size_t)r1 * Ss + k0 + 64 + c1, vd + i1 * 8);
    }

    if (it < my_steps) {
      const hbf* kt = &Ks[buf][0];
      f32x16 st[2] = {};
#pragma unroll
      for (int c = 0; c < 2; ++c) {
        const int krow = l31 + 32 * c;
        const int kr7 = krow & 7;
#pragma unroll
        for (int ds = 0; ds < 4; ++ds) {
          bf16x8 kf = *(const bf16x8*)(kt + krow * 64 + 8 * ((ds * 2 + hi) ^ kr7));
          st[c] = __builtin_amdgcn_mfma_f32_32x32x16_bf16(kf, qf[ds], st[c], 0, 0, 0);
        }
      }

      if (it == my_steps - 1) {
        const int qg = q0w + l31;
#pragma unroll
        for (int c = 0; c < 2; ++c)
#pragma unroll
          for (int rg = 0; rg < 16; ++rg) {
            int kg = k0 + c * 32 + (rg & 3) + 8 * (rg >> 2) + 4 * hi;
            if (kg > qg) st[c][rg] = -3e38f;
          }
      }

      float mx = -3e38f;
#pragma unroll
      for (int c = 0; c < 2; ++c)
#pragma unroll
        for (int rg = 0; rg < 16; ++rg) mx = fmaxf(mx, st[c][rg]);
      mx = fmaxf(mx, __shfl_xor(mx, 32));
      if (!__all(mx - m_run <= 11.541560327111707f)) {
        float mn = fmaxf(m_run, mx);
        float sc = exp2f(m_run - mn);
        m_run = mn;
        l_run *= sc;
#pragma unroll
        for (int dc = 0; dc < 2; ++dc)
#pragma unroll
          for (int rg = 0; rg < 16; ++rg) ot[dc][rg] *= sc;
      }
      float rs = 0.f;
#pragma unroll
      for (int c = 0; c < 2; ++c)
#pragma unroll
        for (int rg = 0; rg < 16; ++rg) {
          float p = exp2f(st[c][rg] - m_run);
          st[c][rg] = p;
          rs += p;
        }
      rs += __shfl_xor(rs, 32);
      l_run += rs;

      bf16x8 pf[2][2];
#pragma unroll
      for (int c = 0; c < 2; ++c)
#pragma unroll
        for (int ks = 0; ks < 2; ++ks) {
          const int rb = ks * 8;
          u32 a0 = pkbf(st[c][rb + 0], st[c][rb + 1]);
          u32 a1 = pkbf(st[c][rb + 2], st[c][rb + 3]);
          u32 b0 = pkbf(st[c][rb + 4], st[c][rb + 5]);
          u32 b1 = pkbf(st[c][rb + 6], st[c][rb + 7]);
          u32 pa0 = __shfl_xor(a0, 32), pa1 = __shfl_xor(a1, 32);
          u32 pb0 = __shfl_xor(b0, 32), pb1 = __shfl_xor(b1, 32);
          u32x4 f;
          f.x = hi ? pb0 : a0;
          f.y = hi ? pb1 : a1;
          f.z = hi ? b0 : pa0;
          f.w = hi ? b1 : pa1;
          pf[c][ks] = __builtin_bit_cast(bf16x8, f);
        }

      const hbf* vtl = &Vs[buf][0];
#pragma unroll
      for (int dc = 0; dc < 2; ++dc) {
        const int vrow = l31 + 32 * dc;
        const int vr7 = vrow & 7;
#pragma unroll
        for (int c = 0; c < 2; ++c)
#pragma unroll
          for (int ks = 0; ks < 2; ++ks) {
            bf16x8 vf = *(const bf16x8*)(vtl + vrow * 64 + 8 * ((c * 4 + ks * 2 + hi) ^ vr7));
            ot[dc] = __builtin_amdgcn_mfma_f32_32x32x16_bf16(vf, pf[c][ks], ot[dc], 0, 0, 0);
          }
      }
    }

    __syncthreads();
    buf ^= 1;
  }

  const float inv = 1.f / l_run;
  hbf* crow = ctx + (size_t)(b * Ss + q0w + l31) * Dm + hh * 64;
#pragma unroll
  for (int dc = 0; dc < 2; ++dc)
#pragma unroll
    for (int rg = 0; rg < 4; ++rg) {
      ushort4 w;
      w.x = f2bfu(ot[dc][rg * 4 + 0] * inv);
      w.y = f2bfu(ot[dc][rg * 4 + 1] * inv);
      w.z = f2bfu(ot[dc][rg * 4 + 2] * inv);
      w.w = f2bfu(ot[dc][rg * 4 + 3] * inv);
      *(ushort4*)(crow + dc * 32 + rg * 8 + hi * 4) = w;
    }
}

// -----------------------------------------------------------------------------------------
extern "C" void kernel_launch(void* const* d_in, const int* in_sizes, int n_in,
                              void* d_out, int out_size, void* d_ws, size_t ws_size,
                              hipStream_t stream) {
  const float* x  = (const float*)d_in[0];
  const float* Wq = (const float*)d_in[1];
  const float* Wk = (const float*)d_in[2];
  const float* Wv = (const float*)d_in[3];
  const float* Wo = (const float*)d_in[4];
  const float* bo = (const float*)d_in[5];
  const float* W1 = (const float*)d_in[6];
  const float* b1 = (const float*)d_in[7];
  const float* W2 = (const float*)d_in[8];
  const float* b2 = (const float*)d_in[9];
  const float* g1 = (const float*)d_in[10];
  const float* s1 = (const float*)d_in[11];
  const float* g2 = (const float*)d_in[12];
  const float* s2 = (const float*)d_in[13];
  float* out = (float*)d_out;

  char* ws = (char*)d_ws;
  constexpr size_t MB = 1024ull * 1024ull;
  hbf* wqkvT = (hbf*)(ws + 0 * MB);    // 6MB [3072][1024]
  hbf* woT   = (hbf*)(ws + 6 * MB);    // 2MB
  hbf* w1T   = (hbf*)(ws + 8 * MB);    // 8MB
  hbf* w2T   = (hbf*)(ws + 16 * MB);   // 8MB
  hbf* xln   = (hbf*)(ws + 24 * MB);   // 16MB (reused: ctx, then y2)
  hbf* ctx   = (hbf*)(ws + 24 * MB);
  hbf* y2    = (hbf*)(ws + 24 * MB);
  hbf* qkvb  = (hbf*)(ws + 40 * MB);   // 48MB [8192][3072]
  hbf* vtb   = (hbf*)(ws + 88 * MB);   // 16MB
  hbf* ff1   = (hbf*)(ws + 40 * MB);   // 64MB (over dead qkv/vt)
  float* hb  = (float*)(ws + 104 * MB); // 32MB fp32
  (void)ws_size; (void)in_sizes; (void)n_in; (void)out_size;

  const int BS = Bb * Ss;  // 8192 rows

  // 1) weights -> bf16 transposed [N,K]; 4 square in one launch, then W1/W2
  wtrans4_kernel<<<dim3(32, 32, 4), 256, 0, stream>>>(Wq, Wk, Wv, Wo,
                                                      wqkvT, wqkvT + 1024 * 1024,
                                                      wqkvT + 2 * 1024 * 1024, woT);
  wtrans_kernel<<<dim3(32, 128), 256, 0, stream>>>(W1, w1T, Dm, DFm);
  wtrans_kernel<<<dim3(128, 32), 256, 0, stream>>>(W2, w2T, DFm, Dm);

  // 2) LN1
  ln_kernel<<<BS, 256, 0, stream>>>(x, g1, s1, xln);

  // 3) fused QKV projection: [8192,1024] @ [1024,3072]  (grid 32*12=384)
  gemm8<256, 2, 4, 0, false, false, true><<<384, 512, 0, stream>>>(xln, wqkvT, qkvb, nullptr, nullptr, BS, LDQ, Dm);

  // 4) V transpose per head
  vtrans_kernel<<<dim3(Ss / 64, Bb * Hh), 256, 0, stream>>>(qkvb, vtb);

  // 5) flash attention
  attn_kernel<<<dim3(1024), 256, 0, stream>>>(qkvb, vtb, ctx);

  // 6) output projection + bias + residual -> h (fp32)  (grid 32*8=256, BN=128)
  gemm8<128, 4, 2, 0, true, true, false><<<256, 512, 0, stream>>>(ctx, woT, hb, bo, x, BS, Dm, Dm);

  // 7) LN2
  ln_kernel<<<BS, 256, 0, stream>>>(hb, g2, s2, y2);

  // 8) FF1 + bias + GELU  (grid 32*16=512)
  gemm8<256, 2, 4, 1, true, false, true><<<512, 512, 0, stream>>>(y2, w1T, ff1, b1, nullptr, BS, DFm, Dm);

  // 9) FF2 + bias + residual -> out (fp32)  (grid 32*8=256, BN=128, K=4096)
  gemm8<128, 4, 2, 0, true, true, false><<<256, 512, 0, stream>>>(ff1, w2T, out, b2, hb, BS, Dm, DFm);
}

// Round 6
// 370.184 us; speedup vs baseline: 2.1537x; 1.0463x over previous
//
#include <hip/hip_runtime.h>
#include <hip/hip_bf16.h>

#define DEV __device__ __forceinline__

typedef __bf16 bf16x8 __attribute__((ext_vector_type(8)));
typedef __bf16 bf16x2v __attribute__((ext_vector_type(2)));
typedef float f32x4 __attribute__((ext_vector_type(4)));
typedef float f32x16 __attribute__((ext_vector_type(16)));
typedef unsigned int u32;
typedef unsigned int u32x4 __attribute__((ext_vector_type(4)));
typedef __hip_bfloat16 hbf;

constexpr int Dm = 1024;
constexpr int Hh = 16;
constexpr int Ss = 2048;
constexpr int Bb = 4;
constexpr int DFm = 4096;
constexpr int LDQ = 3072;  // fused qkv row stride

DEV unsigned short f2bfu(float f) {
  hbf h = __float2bfloat16(f);
  return __builtin_bit_cast(unsigned short, h);
}

DEV float bfu2f(unsigned short u) { return __builtin_bit_cast(float, (u32)u << 16); }

DEV u32 pkbf(float x, float y) {
  bf16x2v v = {(__bf16)x, (__bf16)y};
  return __builtin_bit_cast(u32, v);
}

DEV float gelu_f(float x) {
  // 0.5x(1+tanh(z)) == x * sigmoid(2z); rcp is 1-ulp, fine for bf16-grade output
  float e = __expf(-1.5957691216057308f * (x + 0.044715f * x * x * x));
  return x * __builtin_amdgcn_rcpf(1.f + e);
}

#define GLDS(src, dst)                                                                     \
  __builtin_amdgcn_global_load_lds((const __attribute__((address_space(1))) void*)(src),   \
                                   (__attribute__((address_space(3))) void*)(dst), 16, 0, 0)

// ---------------- all 6 weight transposes (fp32->bf16, W[K,N] -> Wt[N,K]) in one launch ---
__global__ __launch_bounds__(256) void wtransall_kernel(
    const float* __restrict__ Wq, const float* __restrict__ Wk,
    const float* __restrict__ Wv, const float* __restrict__ Wo,
    const float* __restrict__ W1, const float* __restrict__ W2,
    hbf* __restrict__ dqkv, hbf* __restrict__ dwo,
    hbf* __restrict__ dw1, hbf* __restrict__ dw2) {
  __shared__ float tile[32][33];
  const int i = blockIdx.x;
  const float* W;
  hbf* Wt;
  int K, N, k0, n0;
  if (i < 4096) {
    int z = i >> 10, j = i & 1023;
    W = z == 0 ? Wq : z == 1 ? Wk : z == 2 ? Wv : Wo;
    Wt = z == 3 ? dwo : dqkv + (size_t)z * 1024 * 1024;
    K = 1024; N = 1024; k0 = (j & 31) * 32; n0 = (j >> 5) * 32;
  } else if (i < 8192) {
    int j = i - 4096;
    W = W1; Wt = dw1; K = 1024; N = 4096;
    k0 = (j & 31) * 32; n0 = (j >> 5) * 32;
  } else {
    int j = i - 8192;
    W = W2; Wt = dw2; K = 4096; N = 1024;
    k0 = (j & 127) * 32; n0 = (j >> 7) * 32;
  }
  int tx = threadIdx.x & 31, ty = threadIdx.x >> 5;
  for (int r = ty; r < 32; r += 8) tile[r][tx] = W[(size_t)(k0 + r) * N + n0 + tx];
  __syncthreads();
  for (int r = ty; r < 32; r += 8)
    Wt[(size_t)(n0 + r) * K + k0 + tx] = __float2bfloat16(tile[tx][r]);
}

// ---------------- layernorm (fp32 or bf16 in, bf16 out), one block per row ----------------
template <bool INBF>
__global__ __launch_bounds__(256) void ln_kernel(const void* __restrict__ xv,
                                                 const float* __restrict__ g,
                                                 const float* __restrict__ b,
                                                 hbf* __restrict__ y) {
  int row = blockIdx.x;
  int t = threadIdx.x;
  float4 v;
  if constexpr (INBF) {
    ushort4 u = ((const ushort4*)((const hbf*)xv + (size_t)row * Dm))[t];
    v.x = bfu2f(u.x); v.y = bfu2f(u.y); v.z = bfu2f(u.z); v.w = bfu2f(u.w);
  } else {
    v = ((const float4*)((const float*)xv + (size_t)row * Dm))[t];
  }
  float s = v.x + v.y + v.z + v.w;
  float q = v.x * v.x + v.y * v.y + v.z * v.z + v.w * v.w;
#pragma unroll
  for (int off = 32; off > 0; off >>= 1) {
    s += __shfl_down(s, off);
    q += __shfl_down(q, off);
  }
  __shared__ float red[10];
  int wave = t >> 6, lane = t & 63;
  if (lane == 0) { red[wave] = s; red[4 + wave] = q; }
  __syncthreads();
  if (t == 0) {
    float ts = red[0] + red[1] + red[2] + red[3];
    float tq = red[4] + red[5] + red[6] + red[7];
    float mean = ts * (1.f / Dm);
    float var = tq * (1.f / Dm) - mean * mean;
    red[8] = mean;
    red[9] = rsqrtf(var + 1e-5f);
  }
  __syncthreads();
  float mean = red[8], inv = red[9];
  float4 gv = ((const float4*)g)[t];
  float4 bv = ((const float4*)b)[t];
  ushort4 o;
  o.x = f2bfu(gv.x * (v.x - mean) * inv + bv.x);
  o.y = f2bfu(gv.y * (v.y - mean) * inv + bv.y);
  o.z = f2bfu(gv.z * (v.z - mean) * inv + bv.z);
  o.w = f2bfu(gv.w * (v.w - mean) * inv + bv.w);
  ((ushort4*)(y + (size_t)row * Dm))[t] = o;
}

// ================= 8-phase / 2-phase 256-tile GEMM (T2+T3+T4+T5) ==========================
// C[M,N] = A[M,K](bf16) @ Bt[N,K]^T(bf16). BM=256, BK=64, 512 thr = 8 waves (WM x WN).
// Slabs per buffer: A-half(mh) 128 rows x 64, B-half(nh) BN/2 rows x 64 (contiguous 128B
// rows, full-cacheline gload_lds). NPH=4 (BN=256): C-quadrant phases (0,0),(1,0),(1,1),
// (0,1), 16 MFMA each; stages P1:A0+B0(t+2), P2:A1, P3:B1; boundary vmcnt(8).
// NPH=2 (BN=128): phases = nh halves, 16 MFMA each; PA stages B1(t+1)->buf^1, PB stages
// A0,A1,B0(t+2)->buf; boundary vmcnt(5). All slab lifetimes barrier-separated from their
// re-stage. Raw s_barrier only; lgkmcnt(0)+sched_barrier before MFMA (rule 18).
// RES: 0 none, 1 fp32, 2 bf16.
template <int BN, int WM, int WN, int NPH, int ACT, bool HAS_BIAS, int RES, bool OUT_BF16>
__global__ __launch_bounds__(512, 2) void gemm8(const hbf* __restrict__ A,
                                                const hbf* __restrict__ Bt,
                                                void* __restrict__ Cv,
                                                const float* __restrict__ bias,
                                                const void* __restrict__ resv,
                                                int M, int N, int K) {
  constexpr int BM = 256;
  constexpr int MR = (BM / WM) / 16, NR = (BN / WN) / 16;
  constexpr int MQ = MR / 2, NQ = NR / 2;
  constexpr int RPA = (BM / WM) / 2;
  constexpr int RPB = (BN / WN) / 2;
  constexpr int ASL = 128 * 64;
  constexpr int BSL = (BN / 2) * 64;
  constexpr int PERBUF = 2 * ASL + 2 * BSL;
  constexpr int ALD = 2;
  constexpr int BLD = BN / 128;

  __shared__ __align__(16) hbf lds[2 * PERBUF];

  const int tid = threadIdx.x;
  const int lane = tid & 63, wave = tid >> 6;
  const int wr = wave / WN, wc = wave % WN;
  const int lr = lane & 15, lg = lane >> 4;

  // bijective XCD swizzle (m204)
  const int nwg = gridDim.x;
  const int qq = nwg >> 3, rr = nwg & 7;
  const int xcd = blockIdx.x & 7, oidx = blockIdx.x >> 3;
  const int wg = (xcd < rr ? xcd * (qq + 1) : rr * (qq + 1) + (xcd - rr) * qq) + oidx;
  const int ntn = N / BN;
  const int m0 = (wg / ntn) * BM, n0 = (wg % ntn) * BN;

  const hbf* Ab = A + (size_t)m0 * K;
  const hbf* Bb = Bt + (size_t)n0 * K;

  f32x4 acc[MR][NR] = {};

  auto stageA = [&](int mh, int t, int p) {
#pragma unroll
    for (int l = 0; l < ALD; ++l) {
      int ci = l * 512 + tid;
      int r = ci >> 3, c = ci & 7;
      int piece = r / RPA, rl = r % RPA;
      int grow = piece * (BM / WM) + mh * RPA + rl;
      int gk = t * 64 + ((c ^ (r & 7)) << 3);
      GLDS(Ab + (size_t)grow * K + gk, lds + p * PERBUF + mh * ASL + (size_t)ci * 8);
    }
  };
  auto stageB = [&](int nh, int t, int p) {
#pragma unroll
    for (int l = 0; l < BLD; ++l) {
      int ci = l * 512 + tid;
      int r = ci >> 3, c = ci & 7;
      int piece = r / RPB, rl = r % RPB;
      int grow = piece * (BN / WN) + nh * RPB + rl;
      int gk = t * 64 + ((c ^ (r & 7)) << 3);
      GLDS(Bb + (size_t)grow * K + gk, lds + p * PERBUF + 2 * ASL + nh * BSL + (size_t)ci * 8);
    }
  };
  auto ldA = [&](bf16x8 (&af)[MQ][2], int mh, int p) {
    const hbf* base = lds + p * PERBUF + mh * ASL;
#pragma unroll
    for (int i = 0; i < MQ; ++i)
#pragma unroll
      for (int ks = 0; ks < 2; ++ks) {
        int row = wr * RPA + i * 16 + lr;
        int slot = (ks * 4 + lg) ^ (lr & 7);
        af[i][ks] = *(const bf16x8*)(base + (size_t)row * 64 + slot * 8);
      }
  };
  auto ldAfull = [&](bf16x8 (&af)[MR][2], int p) {
#pragma unroll
    for (int f = 0; f < MR; ++f)
#pragma unroll
      for (int ks = 0; ks < 2; ++ks) {
        int mh = f >> 1, i = f & 1;
        const hbf* base = lds + p * PERBUF + mh * ASL;
        int row = wr * RPA + i * 16 + lr;
        int slot = (ks * 4 + lg) ^ (lr & 7);
        af[f][ks] = *(const bf16x8*)(base + (size_t)row * 64 + slot * 8);
      }
  };
  auto ldB = [&](bf16x8 (&bf)[NQ][2], int nh, int p) {
    const hbf* base = lds + p * PERBUF + 2 * ASL + nh * BSL;
#pragma unroll
    for (int j = 0; j < NQ; ++j)
#pragma unroll
      for (int ks = 0; ks < 2; ++ks) {
        int row = wc * RPB + j * 16 + lr;
        int slot = (ks * 4 + lg) ^ (lr & 7);
        bf[j][ks] = *(const bf16x8*)(base + (size_t)row * 64 + slot * 8);
      }
  };

#define SYNC_LGKM()                                        \
  do {                                                     \
    __builtin_amdgcn_s_barrier();                          \
    asm volatile("s_waitcnt lgkmcnt(0)" ::: "memory");     \
    __builtin_amdgcn_sched_barrier(0);                     \
  } while (0)

#define MFMA_Q(av, bv, mh, nh)                                                        \
  do {                                                                                \
    __builtin_amdgcn_s_setprio(1);                                                    \
    _Pragma("unroll") for (int i_ = 0; i_ < MQ; ++i_)                                 \
    _Pragma("unroll") for (int j_ = 0; j_ < NQ; ++j_)                                 \
    _Pragma("unroll") for (int k_ = 0; k_ < 2; ++k_)                                  \
      acc[(mh) * MQ + i_][(nh) * NQ + j_] = __builtin_amdgcn_mfma_f32_16x16x32_bf16(  \
          (av)[i_][k_], (bv)[j_][k_], acc[(mh) * MQ + i_][(nh) * NQ + j_], 0, 0, 0);  \
    __builtin_amdgcn_s_setprio(0);                                                    \
  } while (0)

#define MFMA_H(av, bv, nh)                                                            \
  do {                                                                                \
    __builtin_amdgcn_s_setprio(1);                                                    \
    _Pragma("unroll") for (int f_ = 0; f_ < MR; ++f_)                                 \
    _Pragma("unroll") for (int j_ = 0; j_ < NQ; ++j_)                                 \
    _Pragma("unroll") for (int k_ = 0; k_ < 2; ++k_)                                  \
      acc[f_][(nh) * NQ + j_] = __builtin_amdgcn_mfma_f32_16x16x32_bf16(              \
          (av)[f_][k_], (bv)[j_][k_], acc[f_][(nh) * NQ + j_], 0, 0, 0);              \
    __builtin_amdgcn_s_setprio(0);                                                    \
  } while (0)

  const int T = K >> 6;

  if constexpr (NPH == 4) {
    // prologue: tiles 0,1 fully staged; keep tile1's 8 in flight
    stageA(0, 0, 0); stageB(0, 0, 0); stageA(1, 0, 0); stageB(1, 0, 0);
    stageA(0, 1, 1); stageB(0, 1, 1); stageA(1, 1, 1); stageB(1, 1, 1);
    asm volatile("s_waitcnt vmcnt(8)" ::: "memory");
    __builtin_amdgcn_s_barrier();

    for (int t = 0; t < T; ++t) {
      const int p = t & 1;
      bf16x8 a0[MQ][2], a1[MQ][2], b0[NQ][2], b1[NQ][2];
      // P0: quadrant (0,0)
      ldA(a0, 0, p);
      ldB(b0, 0, p);
      asm volatile("s_waitcnt lgkmcnt(8)" ::: "memory");
      SYNC_LGKM();
      MFMA_Q(a0, b0, 0, 0);
      __builtin_amdgcn_s_barrier();
      // P1: quadrant (1,0); stage A0+B0(t+2)
      ldA(a1, 1, p);
      if (t + 2 < T) { stageA(0, t + 2, p); stageB(0, t + 2, p); }
      SYNC_LGKM();
      MFMA_Q(a1, b0, 1, 0);
      __builtin_amdgcn_s_barrier();
      // P2: quadrant (1,1); stage A1(t+2)
      ldB(b1, 1, p);
      if (t + 2 < T) stageA(1, t + 2, p);
      SYNC_LGKM();
      MFMA_Q(a1, b1, 1, 1);
      __builtin_amdgcn_s_barrier();
      // P3: quadrant (0,1); stage B1(t+2); boundary vmcnt
      if (t + 2 < T) stageB(1, t + 2, p);
      MFMA_Q(a0, b1, 0, 1);
      if (t + 1 < T) {
        if (t + 2 < T) asm volatile("s_waitcnt vmcnt(8)" ::: "memory");
        else asm volatile("s_waitcnt vmcnt(0)" ::: "memory");
      }
      __builtin_amdgcn_s_barrier();
    }
  } else {
    // NPH==2: prologue = tile0 full (6), tile1 minus B1 (5); keep tile1's 5
    stageA(0, 0, 0); stageA(1, 0, 0); stageB(0, 0, 0); stageB(1, 0, 0);
    stageA(0, 1, 1); stageA(1, 1, 1); stageB(0, 1, 1);
    asm volatile("s_waitcnt vmcnt(5)" ::: "memory");
    __builtin_amdgcn_s_barrier();

    for (int t = 0; t < T; ++t) {
      const int p = t & 1;
      bf16x8 af[MR][2], b0[NQ][2], b1[NQ][2];
      // PA: all-A x nh0; stage B1(t+1) -> buf p^1
      ldAfull(af, p);
      ldB(b0, 0, p);
      if (t + 1 < T) stageB(1, t + 1, p ^ 1);
      asm volatile("s_waitcnt lgkmcnt(8)" ::: "memory");
      SYNC_LGKM();
      MFMA_H(af, b0, 0);
      __builtin_amdgcn_s_barrier();
      // PB: all-A x nh1; stage A0,A1,B0(t+2) -> buf p; boundary vmcnt
      ldB(b1, 1, p);
      if (t + 2 < T) { stageA(0, t + 2, p); stageA(1, t + 2, p); stageB(0, t + 2, p); }
      SYNC_LGKM();
      MFMA_H(af, b1, 1);
      if (t + 1 < T) {
        if (t + 2 < T) asm volatile("s_waitcnt vmcnt(5)" ::: "memory");
        else asm volatile("s_waitcnt vmcnt(0)" ::: "memory");
      }
      __builtin_amdgcn_s_barrier();
    }
  }
#undef SYNC_LGKM
#undef MFMA_Q
#undef MFMA_H

  // ---- epilogue ----
#pragma unroll
  for (int mf = 0; mf < MR; ++mf) {
    int row = m0 + wr * (BM / WM) + mf * 16 + lg * 4;
#pragma unroll
    for (int n = 0; n < NR; ++n) {
      int col = n0 + wc * (BN / WN) + n * 16 + lr;
      float bvl = HAS_BIAS ? bias[col] : 0.f;
#pragma unroll
      for (int j = 0; j < 4; ++j) {
        float v = acc[mf][n][j] + bvl;
        if (ACT == 1) v = gelu_f(v);
        if constexpr (RES == 1) v += ((const float*)resv)[(size_t)(row + j) * N + col];
        else if constexpr (RES == 2)
          v += bfu2f(__builtin_bit_cast(unsigned short,
                                        ((const hbf*)resv)[(size_t)(row + j) * N + col]));
        if (OUT_BF16) ((hbf*)Cv)[(size_t)(row + j) * N + col] = __float2bfloat16(v);
        else ((float*)Cv)[(size_t)(row + j) * N + col] = v;
      }
    }
  }
}

// ---------------- per-head V transpose: qkv[b,s,2048+h*64+d] -> vt[(b*H+h)*64+d, s] -------
__global__ __launch_bounds__(256) void vtrans_kernel(const hbf* __restrict__ qkv,
                                                     hbf* __restrict__ vt) {
  __shared__ unsigned short tile[64][65];
  int bh = blockIdx.y, b = bh >> 4, hh = bh & 15;
  int s0 = blockIdx.x * 64;
  int d = threadIdx.x & 63, r0 = threadIdx.x >> 6;
#pragma unroll
  for (int i = 0; i < 16; ++i) {
    int r = r0 * 16 + i;
    tile[d][r] = __builtin_bit_cast(unsigned short,
                                    qkv[(size_t)(b * Ss + s0 + r) * LDQ + 2048 + hh * 64 + d]);
  }
  __syncthreads();
#pragma unroll
  for (int i = 0; i < 16; ++i) {
    int r = r0 * 16 + i;
    vt[(size_t)(bh * 64 + r) * Ss + s0 + d] = __builtin_bit_cast(hbf, tile[r][d]);
  }
}

// ---------------- causal flash attention, swapped QK^T, in-register softmax ---------------
__global__ __launch_bounds__(256, 3) void attn_kernel(const hbf* __restrict__ qkv,
                                                      const hbf* __restrict__ vt,
                                                      hbf* __restrict__ ctx) {
  __shared__ __align__(16) hbf Ks[2][64 * 64];
  __shared__ __align__(16) hbf Vs[2][64 * 64];

  const int tid = threadIdx.x;
  const int wave = tid >> 6, lane = tid & 63;
  const int l31 = lane & 31, hi = lane >> 5;

  const int gi = blockIdx.x;
  const int g = gi >> 9, rr_ = gi & 511;
  const int bh = rr_ >> 3, j = rr_ & 7;
  const int bx = g ? j : 15 - j;
  const int b = bh >> 4, hh = bh & 15;
  const int q0b = bx * 128;
  const int q0w = q0b + wave * 32;
  const int nsteps = (q0b + 128) >> 6;
  const int my_steps = (q0w + 95) >> 6;

  constexpr float QSCALE = 0.18033688011112042f;  // 0.125 * log2(e)
  bf16x8 qf[4];
  {
    const hbf* qrow = qkv + (size_t)(b * Ss + q0w + l31) * LDQ + hh * 64 + hi * 8;
#pragma unroll
    for (int ds = 0; ds < 4; ++ds) {
      bf16x8 t = *(const bf16x8*)(qrow + ds * 16);
#pragma unroll
      for (int e = 0; e < 8; ++e) qf[ds][e] = (__bf16)((float)t[e] * QSCALE);
    }
  }

  const hbf* kbase = qkv + 1024 + (size_t)(b * Ss) * LDQ + hh * 64;
  const hbf* vbase = vt + (size_t)(bh * 64) * Ss;
  const int i0 = tid, i1 = tid + 256;
  const int r0 = i0 >> 3, s0c = (i0 & 7), r1 = i1 >> 3, s1c = (i1 & 7);
  const int c0 = 8 * (s0c ^ (r0 & 7)), c1 = 8 * (s1c ^ (r1 & 7));

  f32x16 ot[2] = {};
  float m_run = -1e30f, l_run = 0.f;

  {
    hbf* kd = &Ks[0][0];
    hbf* vd = &Vs[0][0];
    GLDS(kbase + (size_t)r0 * LDQ + c0, kd + i0 * 8);
    GLDS(kbase + (size_t)r1 * LDQ + c1, kd + i1 * 8);
    GLDS(vbase + (size_t)r0 * Ss + c0, vd + i0 * 8);
    GLDS(vbase + (size_t)r1 * Ss + c1, vd + i1 * 8);
  }
  __syncthreads();

  int buf = 0;
  for (int it = 0; it < nsteps; ++it) {
    const int k0 = it << 6;
    if (it + 1 < nsteps) {
      hbf* kd = &Ks[buf ^ 1][0];
      hbf* vd = &Vs[buf ^ 1][0];
      GLDS(kbase + (size_t)(k0 + 64 + r0) * LDQ + c0, kd + i0 * 8);
      GLDS(kbase + (size_t)(k0 + 64 + r1) * LDQ + c1, kd + i1 * 8);
      GLDS(vbase + (size_t)r0 * Ss + k0 + 64 + c0, vd + i0 * 8);
      GLDS(vbase + (size_t)r1 * Ss + k0 + 64 + c1, vd + i1 * 8);
    }

    if (it < my_steps) {
      const hbf* kt = &Ks[buf][0];
      f32x16 st[2] = {};
      __builtin_amdgcn_s_setprio(1);
#pragma unroll
      for (int c = 0; c < 2; ++c) {
        const int krow = l31 + 32 * c;
        const int kr7 = krow & 7;
#pragma unroll
        for (int ds = 0; ds < 4; ++ds) {
          bf16x8 kf = *(const bf16x8*)(kt + krow * 64 + 8 * ((ds * 2 + hi) ^ kr7));
          st[c] = __builtin_amdgcn_mfma_f32_32x32x16_bf16(kf, qf[ds], st[c], 0, 0, 0);
        }
      }
      __builtin_amdgcn_s_setprio(0);

      if (it == my_steps - 1) {
        const int qg = q0w + l31;
#pragma unroll
        for (int c = 0; c < 2; ++c)
#pragma unroll
          for (int rg = 0; rg < 16; ++rg) {
            int kg = k0 + c * 32 + (rg & 3) + 8 * (rg >> 2) + 4 * hi;
            if (kg > qg) st[c][rg] = -3e38f;
          }
      }

      float mx = -3e38f;
#pragma unroll
      for (int c = 0; c < 2; ++c)
#pragma unroll
        for (int rg = 0; rg < 16; ++rg) mx = fmaxf(mx, st[c][rg]);
      mx = fmaxf(mx, __shfl_xor(mx, 32));
      if (!__all(mx - m_run <= 11.541560327111707f)) {
        float mn = fmaxf(m_run, mx);
        float sc = exp2f(m_run - mn);
        m_run = mn;
        l_run *= sc;
#pragma unroll
        for (int dc = 0; dc < 2; ++dc)
#pragma unroll
          for (int rg = 0; rg < 16; ++rg) ot[dc][rg] *= sc;
      }
      float rs = 0.f;
#pragma unroll
      for (int c = 0; c < 2; ++c)
#pragma unroll
        for (int rg = 0; rg < 16; ++rg) {
          float p = exp2f(st[c][rg] - m_run);
          st[c][rg] = p;
          rs += p;
        }
      rs += __shfl_xor(rs, 32);
      l_run += rs;

      bf16x8 pf[2][2];
#pragma unroll
      for (int c = 0; c < 2; ++c)
#pragma unroll
        for (int ks = 0; ks < 2; ++ks) {
          const int rb = ks * 8;
          u32 a0 = pkbf(st[c][rb + 0], st[c][rb + 1]);
          u32 a1 = pkbf(st[c][rb + 2], st[c][rb + 3]);
          u32 b0 = pkbf(st[c][rb + 4], st[c][rb + 5]);
          u32 b1 = pkbf(st[c][rb + 6], st[c][rb + 7]);
          u32 pa0 = __shfl_xor(a0, 32), pa1 = __shfl_xor(a1, 32);
          u32 pb0 = __shfl_xor(b0, 32), pb1 = __shfl_xor(b1, 32);
          u32x4 f;
          f.x = hi ? pb0 : a0;
          f.y = hi ? pb1 : a1;
          f.z = hi ? b0 : pa0;
          f.w = hi ? b1 : pa1;
          pf[c][ks] = __builtin_bit_cast(bf16x8, f);
        }

      const hbf* vtl = &Vs[buf][0];
      __builtin_amdgcn_s_setprio(1);
#pragma unroll
      for (int dc = 0; dc < 2; ++dc) {
        const int vrow = l31 + 32 * dc;
        const int vr7 = vrow & 7;
#pragma unroll
        for (int c = 0; c < 2; ++c)
#pragma unroll
          for (int ks = 0; ks < 2; ++ks) {
            bf16x8 vf = *(const bf16x8*)(vtl + vrow * 64 + 8 * ((c * 4 + ks * 2 + hi) ^ vr7));
            ot[dc] = __builtin_amdgcn_mfma_f32_32x32x16_bf16(vf, pf[c][ks], ot[dc], 0, 0, 0);
          }
      }
      __builtin_amdgcn_s_setprio(0);
    }

    __syncthreads();
    buf ^= 1;
  }

  const float inv = __builtin_amdgcn_rcpf(l_run);
  hbf* crow = ctx + (size_t)(b * Ss + q0w + l31) * Dm + hh * 64;
#pragma unroll
  for (int dc = 0; dc < 2; ++dc)
#pragma unroll
    for (int rg = 0; rg < 4; ++rg) {
      ushort4 w;
      w.x = f2bfu(ot[dc][rg * 4 + 0] * inv);
      w.y = f2bfu(ot[dc][rg * 4 + 1] * inv);
      w.z = f2bfu(ot[dc][rg * 4 + 2] * inv);
      w.w = f2bfu(ot[dc][rg * 4 + 3] * inv);
      *(ushort4*)(crow + dc * 32 + rg * 8 + hi * 4) = w;
    }
}

// -----------------------------------------------------------------------------------------
extern "C" void kernel_launch(void* const* d_in, const int* in_sizes, int n_in,
                              void* d_out, int out_size, void* d_ws, size_t ws_size,
                              hipStream_t stream) {
  const float* x  = (const float*)d_in[0];
  const float* Wq = (const float*)d_in[1];
  const float* Wk = (const float*)d_in[2];
  const float* Wv = (const float*)d_in[3];
  const float* Wo = (const float*)d_in[4];
  const float* bo = (const float*)d_in[5];
  const float* W1 = (const float*)d_in[6];
  const float* b1 = (const float*)d_in[7];
  const float* W2 = (const float*)d_in[8];
  const float* b2 = (const float*)d_in[9];
  const float* g1 = (const float*)d_in[10];
  const float* s1 = (const float*)d_in[11];
  const float* g2 = (const float*)d_in[12];
  const float* s2 = (const float*)d_in[13];
  float* out = (float*)d_out;

  char* ws = (char*)d_ws;
  constexpr size_t MB = 1024ull * 1024ull;
  hbf* wqkvT = (hbf*)(ws + 0 * MB);    // 6MB [3072][1024]
  hbf* woT   = (hbf*)(ws + 6 * MB);    // 2MB
  hbf* w1T   = (hbf*)(ws + 8 * MB);    // 8MB
  hbf* w2T   = (hbf*)(ws + 16 * MB);   // 8MB
  hbf* xln   = (hbf*)(ws + 24 * MB);   // 16MB (reused: ctx, then y2)
  hbf* ctx   = (hbf*)(ws + 24 * MB);
  hbf* y2    = (hbf*)(ws + 24 * MB);
  hbf* qkvb  = (hbf*)(ws + 40 * MB);   // 48MB [8192][3072]
  hbf* vtb   = (hbf*)(ws + 88 * MB);   // 16MB
  hbf* ff1   = (hbf*)(ws + 40 * MB);   // 64MB (over dead qkv/vt)
  hbf* hbb   = (hbf*)(ws + 104 * MB);  // 16MB bf16 residual trunk
  (void)ws_size; (void)in_sizes; (void)n_in; (void)out_size;

  const int BS = Bb * Ss;  // 8192 rows

  // 1) all weights -> bf16 transposed [N,K] (one launch)
  wtransall_kernel<<<12288, 256, 0, stream>>>(Wq, Wk, Wv, Wo, W1, W2,
                                              wqkvT, woT, w1T, w2T);

  // 2) LN1
  ln_kernel<false><<<BS, 256, 0, stream>>>(x, g1, s1, xln);

  // 3) fused QKV projection: [8192,1024] @ [1024,3072]
  gemm8<256, 2, 4, 4, 0, false, 0, true><<<384, 512, 0, stream>>>(xln, wqkvT, qkvb, nullptr, nullptr, BS, LDQ, Dm);

  // 4) V transpose per head
  vtrans_kernel<<<dim3(Ss / 64, Bb * Hh), 256, 0, stream>>>(qkvb, vtb);

  // 5) flash attention
  attn_kernel<<<dim3(1024), 256, 0, stream>>>(qkvb, vtb, ctx);

  // 6) output projection + bias + residual(x fp32) -> h (bf16)
  gemm8<128, 4, 2, 2, 0, true, 1, true><<<256, 512, 0, stream>>>(ctx, woT, hbb, bo, x, BS, Dm, Dm);

  // 7) LN2 (bf16 in)
  ln_kernel<true><<<BS, 256, 0, stream>>>(hbb, g2, s2, y2);

  // 8) FF1 + bias + GELU
  gemm8<256, 2, 4, 4, 1, true, 0, true><<<512, 512, 0, stream>>>(y2, w1T, ff1, b1, nullptr, BS, DFm, Dm);

  // 9) FF2 + bias + residual(h bf16) -> out (fp32)
  gemm8<128, 4, 2, 2, 0, true, 2, false><<<256, 512, 0, stream>>>(ff1, w2T, out, b2, hbb, BS, Dm, DFm);
}